// Round 4
// baseline (1715.846 us; speedup 1.0000x reference)
//
#include <hip/hip_runtime.h>
#include <math.h>

#define HH 480
#define WW 640
#define NPIX (HH*WW)
#define NACC 29           // 21 (A upper tri) + 6 (b) + 1 (sum r_icp^2) + 1 (sum r_rgb^2)
#define TPB 256
#define PXPT 3
#define MB 400            // 400 * 256 * 3 = 307200 = NPIX, exact

// d_ws float-index layout:
//   [0..63]        barrier (2 ints used), zeroed by hipMemsetAsync each launch
//   [WS_P0 ..)     partials buf A (transposed [q][block]), NACC*MB floats
//   [WS_P1 ..)     partials buf B
//   big variant only:
//   [WS_G4 ..)     float4 per pixel: (gray, gx, gy, 0)          NPIX*4 floats
//   [WS_PN ..)     2x float4 per pixel: (qx,qy,qz,nqx),(nqy,nqz,0,0)  NPIX*8 floats
#define WS_P0 64
#define WS_P1 (WS_P0 + NACC*MB)          // 11664
#define WS_SMALL_END (WS_P1 + NACC*MB)   // 23264 floats (~93 KB)
#define WS_G4 23296                      // 16B-aligned float index
#define WS_PN (WS_G4 + NPIX*4)           // 1252096
#define WS_BIG_END (WS_PN + NPIX*8)      // 3709696 floats (~14.84 MB)

__device__ __forceinline__ float gradu(const float* g, int v, int u) {
    const float* row = g + v * WW;
    if (u == 0)      return row[1] - row[0];
    if (u == WW - 1) return row[WW - 1] - row[WW - 2];
    return 0.5f * (row[u + 1] - row[u - 1]);
}
__device__ __forceinline__ float gradv(const float* g, int v, int u) {
    if (v == 0)      return g[WW + u] - g[u];
    if (v == HH - 1) return g[(HH - 1) * WW + u] - g[(HH - 2) * WW + u];
    return 0.5f * (g[(v + 1) * WW + u] - g[(v - 1) * WW + u]);
}

__device__ void exp_se3_f32(const float* xi, float* T) {
    float v0 = xi[0], v1 = xi[1], v2 = xi[2];
    float w0 = xi[3], w1 = xi[4], w2 = xi[5];
    float th2 = w0 * w0 + w1 * w1 + w2 * w2;
    float th = sqrtf(th2);
    bool small = th < 1e-8f;
    float ths = small ? 1.0f : th;
    float A = small ? (1.0f - th2 / 6.0f) : (sinf(ths) / ths);
    float B = small ? (0.5f - th2 / 24.0f) : ((1.0f - cosf(ths)) / (ths * ths));
    float C = small ? (1.0f / 6.0f - th2 / 120.0f) : ((ths - sinf(ths)) / (ths * ths * ths));
    float Wx[9] = { 0.f, -w2,  w1,
                    w2,  0.f, -w0,
                   -w1,  w0,  0.f };
    float W2[9];
    #pragma unroll
    for (int i = 0; i < 3; i++)
        #pragma unroll
        for (int j = 0; j < 3; j++) {
            float s = 0.f;
            #pragma unroll
            for (int k = 0; k < 3; k++) s += Wx[i * 3 + k] * Wx[k * 3 + j];
            W2[i * 3 + j] = s;
        }
    float R[9], V[9];
    #pragma unroll
    for (int i = 0; i < 9; i++) {
        float id = (i == 0 || i == 4 || i == 8) ? 1.0f : 0.0f;
        R[i] = id + A * Wx[i] + B * W2[i];
        V[i] = id + B * Wx[i] + C * W2[i];
    }
    float t0 = V[0] * v0 + V[1] * v1 + V[2] * v2;
    float t1 = V[3] * v0 + V[4] * v1 + V[5] * v2;
    float t2 = V[6] * v0 + V[7] * v1 + V[8] * v2;
    T[0] = R[0]; T[1] = R[1]; T[2]  = R[2]; T[3]  = t0;
    T[4] = R[3]; T[5] = R[4]; T[6]  = R[5]; T[7]  = t1;
    T[8] = R[6]; T[9] = R[7]; T[10] = R[8]; T[11] = t2;
    T[12] = 0.f; T[13] = 0.f; T[14] = 0.f; T[15] = 1.f;
}

__device__ __forceinline__ void accum_point(float* acc, const float* J, float r, float w, int costslot) {
    int k = 0;
    #pragma unroll
    for (int i = 0; i < 6; i++) {
        #pragma unroll
        for (int j = i; j < 6; j++) { acc[k] += w * (J[i] * J[j]); k++; }
        acc[21 + i] += w * (J[i] * r);
    }
    acc[costslot] += r * r;
}

// Generation grid barrier: bar[0]=arrive counter, bar[1]=generation.
// Requires all blocks co-resident (grid=400 <= 512 slots @ __launch_bounds__(256,2)).
__device__ __forceinline__ void grid_barrier(int* bar, int nb) {
    __syncthreads();
    if (threadIdx.x == 0) {
        __threadfence();   // release: make this block's global writes device-visible
        int g = __hip_atomic_load(bar + 1, __ATOMIC_RELAXED, __HIP_MEMORY_SCOPE_AGENT);
        int a = __hip_atomic_fetch_add(bar, 1, __ATOMIC_ACQ_REL, __HIP_MEMORY_SCOPE_AGENT);
        if (a == nb - 1) {
            __hip_atomic_store(bar, 0, __ATOMIC_RELAXED, __HIP_MEMORY_SCOPE_AGENT);
            __hip_atomic_fetch_add(bar + 1, 1, __ATOMIC_RELEASE, __HIP_MEMORY_SCOPE_AGENT);
        } else {
            while (__hip_atomic_load(bar + 1, __ATOMIC_ACQUIRE, __HIP_MEMORY_SCOPE_AGENT) == g) {
                __builtin_amdgcn_s_sleep(2);
            }
        }
        __threadfence();   // acquire: invalidate stale cached lines before reads
    }
    __syncthreads();
}

template <int PACKED>
__global__ __launch_bounds__(TPB, 2) void fused_icp(
    const float* __restrict__ depth_ref,
    const float* __restrict__ normals_ref,
    const float* __restrict__ gray_ref,
    const float* __restrict__ gray_target,
    const float* __restrict__ points_target,
    const float* __restrict__ normals_target,
    const float* __restrict__ K,
    float* __restrict__ ws,
    float* __restrict__ out)
{
    const int tid = threadIdx.x;
    const int bid = blockIdx.x;
    const float fx = K[0], cx = K[2], fy = K[4], cy = K[5];
    int* bar = (int*)ws;
    float4* g4 = (float4*)(ws + WS_G4);
    float4* pn = (float4*)(ws + WS_PN);

    // ---- one-time packed-texture precompute (big variant only) ----
    if (PACKED) {
        int base = bid * (TPB * PXPT) + tid;
        #pragma unroll
        for (int k = 0; k < PXPT; k++) {
            int p = base + k * TPB;
            int v = p / WW, u = p - v * WW;
            float4 c;
            c.x = gray_target[p];
            c.y = gradu(gray_target, v, u);
            c.z = gradv(gray_target, v, u);
            c.w = 0.f;
            g4[p] = c;
            float4 a, b;
            a.x = points_target[3 * p];
            a.y = points_target[3 * p + 1];
            a.z = points_target[3 * p + 2];
            a.w = normals_target[3 * p];
            b.x = normals_target[3 * p + 1];
            b.y = normals_target[3 * p + 2];
            b.z = 0.f; b.w = 0.f;
            pn[2 * p] = a;
            pn[2 * p + 1] = b;
        }
        grid_barrier(bar, MB);
    }

    // ---- per-block pose state in LDS (identical across blocks every iter) ----
    __shared__ float sR[9], st_[3], sx[6];
    __shared__ float sconv, scost;
    __shared__ float lds[4][NACC];
    __shared__ double part8[NACC * 8];
    __shared__ double sums[NACC];

    if (tid == 0) {
        sR[0] = 1.f; sR[1] = 0.f; sR[2] = 0.f;
        sR[3] = 0.f; sR[4] = 1.f; sR[5] = 0.f;
        sR[6] = 0.f; sR[7] = 0.f; sR[8] = 1.f;
        st_[0] = 0.f; st_[1] = 0.f; st_[2] = 0.f;
        #pragma unroll
        for (int i = 0; i < 6; i++) sx[i] = 0.f;
        sconv = 0.f; scost = 0.f;
    }
    __syncthreads();

    for (int it = 0; it < 20; ++it) {
        const float R00 = sR[0], R01 = sR[1], R02 = sR[2];
        const float R10 = sR[3], R11 = sR[4], R12 = sR[5];
        const float R20 = sR[6], R21 = sR[7], R22 = sR[8];
        const float t0 = st_[0], t1 = st_[1], t2 = st_[2];

        float acc[NACC];
        #pragma unroll
        for (int i = 0; i < NACC; i++) acc[i] = 0.f;

        int pbase = bid * (TPB * PXPT) + tid;
        #pragma unroll
        for (int kk = 0; kk < PXPT; kk++) {
            int p = pbase + kk * TPB;
            int vv = p / WW;
            int uu = p - vv * WW;

            float Z = depth_ref[p];
            float Px = ((float)uu - cx) / fx * Z;
            float Py = ((float)vv - cy) / fy * Z;
            float Pz = Z;
            float Ptx = R00 * Px + R01 * Py + R02 * Pz + t0;
            float Pty = R10 * Px + R11 * Py + R12 * Pz + t1;
            float Ptz = R20 * Px + R21 * Py + R22 * Pz + t2;
            bool okz = Ptz > 1e-6f;
            float Zs = okz ? Ptz : 1.0f;
            float u = fx * Ptx / Zs + cx;
            float v = fy * Pty / Zs + cy;
            bool inb = okz && (u >= 0.f) && (u <= (float)(WW - 1)) && (v >= 0.f) && (v <= (float)(HH - 1));
            if (!inb) continue;

            // ---- ICP term ----
            int ui = (int)rintf(u); ui = ui < 0 ? 0 : (ui > WW - 1 ? WW - 1 : ui);
            int vi = (int)rintf(v); vi = vi < 0 ? 0 : (vi > HH - 1 ? HH - 1 : vi);
            int ti = vi * WW + ui;
            float qx, qy, qz, nqx, nqy, nqz;
            if (PACKED) {
                float4 a = pn[2 * ti], b = pn[2 * ti + 1];
                qx = a.x; qy = a.y; qz = a.z; nqx = a.w; nqy = b.x; nqz = b.y;
            } else {
                qx = points_target[3 * ti]; qy = points_target[3 * ti + 1]; qz = points_target[3 * ti + 2];
                nqx = normals_target[3 * ti]; nqy = normals_target[3 * ti + 1]; nqz = normals_target[3 * ti + 2];
            }
            float dx = Ptx - qx, dy = Pty - qy, dz = Ptz - qz;
            float nr0 = normals_ref[3 * p], nr1 = normals_ref[3 * p + 1], nr2 = normals_ref[3 * p + 2];
            float nrx = R00 * nr0 + R01 * nr1 + R02 * nr2;
            float nry = R10 * nr0 + R11 * nr1 + R12 * nr2;
            float nrz = R20 * nr0 + R21 * nr1 + R22 * nr2;
            const float DIST2 = (float)((200.0 / 15.0) * (200.0 / 15.0));
            if ((dx * dx + dy * dy + dz * dz) < DIST2 &&
                (nrx * nqx + nry * nqy + nrz * nqz) > 0.94f) {
                float r = nqx * dx + nqy * dy + nqz * dz;
                float J[6] = { nqx, nqy, nqz,
                               Pty * nqz - Ptz * nqy,
                               Ptz * nqx - Ptx * nqz,
                               Ptx * nqy - Pty * nqx };
                accum_point(acc, J, r, 10.0f, 27);
            }
            // ---- RGB (photometric) term ----
            float u0f = floorf(u), v0f = floorf(v);
            float du = u - u0f, dv = v - v0f;
            int u0 = (int)u0f; u0 = u0 < 0 ? 0 : (u0 > WW - 1 ? WW - 1 : u0);
            int u1 = (u0 + 1 > WW - 1) ? WW - 1 : u0 + 1;
            int v0 = (int)v0f; v0 = v0 < 0 ? 0 : (v0 > HH - 1 ? HH - 1 : v0);
            int v1 = (v0 + 1 > HH - 1) ? HH - 1 : v0 + 1;
            int i00 = v0 * WW + u0, i01 = v0 * WW + u1, i10 = v1 * WW + u0, i11 = v1 * WW + u1;
            float I00, I01, I10, I11, gx00, gx01, gx10, gx11, gy00, gy01, gy10, gy11;
            if (PACKED) {
                float4 c00 = g4[i00], c01 = g4[i01], c10 = g4[i10], c11 = g4[i11];
                I00 = c00.x; gx00 = c00.y; gy00 = c00.z;
                I01 = c01.x; gx01 = c01.y; gy01 = c01.z;
                I10 = c10.x; gx10 = c10.y; gy10 = c10.z;
                I11 = c11.x; gx11 = c11.y; gy11 = c11.z;
            } else {
                const float* g = gray_target;
                I00 = g[i00]; I01 = g[i01]; I10 = g[i10]; I11 = g[i11];
                gx00 = gradu(g, v0, u0); gx01 = gradu(g, v0, u1);
                gx10 = gradu(g, v1, u0); gx11 = gradu(g, v1, u1);
                gy00 = gradv(g, v0, u0); gy01 = gradv(g, v0, u1);
                gy10 = gradv(g, v1, u0); gy11 = gradv(g, v1, u1);
            }
            float It  = (I00 * (1.f - du) + I01 * du) * (1.f - dv) + (I10 * (1.f - du) + I11 * du) * dv;
            float gxs = (gx00 * (1.f - du) + gx01 * du) * (1.f - dv) + (gx10 * (1.f - du) + gx11 * du) * dv;
            float gys = (gy00 * (1.f - du) + gy01 * du) * (1.f - dv) + (gy10 * (1.f - du) + gy11 * du) * dv;
            float rr = It - gray_ref[p];
            float gpx = gxs * fx / Zs;
            float gpy = gys * fy / Zs;
            float gpz = -(gxs * fx * Ptx + gys * fy * Pty) / (Zs * Zs);
            float J[6] = { gpx, gpy, gpz,
                           Pty * gpz - Ptz * gpy,
                           Ptz * gpx - Ptx * gpz,
                           Ptx * gpy - Pty * gpx };
            accum_point(acc, J, rr, 1.0f, 28);
        }

        // ---- deterministic in-block reduction: wave shuffle -> LDS ----
        #pragma unroll
        for (int q = 0; q < NACC; q++) {
            float vq = acc[q];
            #pragma unroll
            for (int off = 32; off >= 1; off >>= 1) vq += __shfl_xor(vq, off);
            acc[q] = vq;
        }
        int wave = tid >> 6;
        int lane = tid & 63;
        __syncthreads();   // protect lds[][] reuse across iterations
        if (lane == 0) {
            #pragma unroll
            for (int q = 0; q < NACC; q++) lds[wave][q] = acc[q];
        }
        __syncthreads();
        float* pbuf = ws + ((it & 1) ? WS_P1 : WS_P0);
        if (tid < NACC) {
            int q = tid;
            float s = lds[0][q] + lds[1][q] + lds[2][q] + lds[3][q];
            pbuf[q * MB + bid] = s;   // transposed: [q][block]
        }
        grid_barrier(bar, MB);

        // ---- every block redundantly reduces all partials + solves (f64) ----
        if (tid < NACC * 8) {
            int q = tid >> 3, s = tid & 7;
            const int CH = MB / 8;            // 50
            int lo = s * CH, hi = lo + CH;
            const float* row = pbuf + q * MB;
            double a0 = 0.0, a1 = 0.0, a2 = 0.0, a3 = 0.0;
            int i = lo;
            for (; i + 4 <= hi; i += 4) {
                a0 += (double)row[i];
                a1 += (double)row[i + 1];
                a2 += (double)row[i + 2];
                a3 += (double)row[i + 3];
            }
            for (; i < hi; i++) a0 += (double)row[i];
            part8[tid] = ((a0 + a1) + (a2 + a3));
        }
        __syncthreads();
        if (tid < NACC) {
            double sm = 0.0;
            #pragma unroll
            for (int s = 0; s < 8; s++) sm += part8[tid * 8 + s];
            sums[tid] = sm;
        }
        __syncthreads();
        if (tid == 0) {
            double M[6][7];
            int k = 0;
            for (int i = 0; i < 6; i++)
                for (int j = i; j < 6; j++) { M[i][j] = sums[k]; M[j][i] = sums[k]; k++; }
            for (int i = 0; i < 6; i++) { M[i][6] = sums[21 + i]; M[i][i] += 1e-9; }
            double new_cost = 10.0 * sums[27] / (double)NPIX + sums[28] / (double)NPIX;

            for (int c = 0; c < 6; c++) {
                int piv = c; double mx = fabs(M[c][c]);
                for (int r2 = c + 1; r2 < 6; r2++) {
                    double a = fabs(M[r2][c]);
                    if (a > mx) { mx = a; piv = r2; }
                }
                if (piv != c)
                    for (int j2 = 0; j2 < 7; j2++) { double tmp = M[c][j2]; M[c][j2] = M[piv][j2]; M[piv][j2] = tmp; }
                double inv = 1.0 / M[c][c];
                for (int r2 = c + 1; r2 < 6; r2++) {
                    double f = M[r2][c] * inv;
                    for (int j2 = c; j2 < 7; j2++) M[r2][j2] -= f * M[c][j2];
                }
            }
            double x0[6];
            for (int i = 5; i >= 0; i--) {
                double s = M[i][6];
                for (int j = i + 1; j < 6; j++) s -= M[i][j] * x0[j];
                x0[i] = s / M[i][i];
            }

            double nx0 = 0.0, nx = 0.0;
            float xf[6];
            for (int i = 0; i < 6; i++) {
                xf[i] = sx[i];
                nx0 += x0[i] * x0[i];
                nx  += (double)xf[i] * (double)xf[i];
            }
            nx0 = sqrt(nx0); nx = sqrt(nx);
            bool convold = (sconv != 0.f);
            bool c2 = convold || (new_cost < 1e-3) || (nx0 < 1e-8 * (1e-8 + nx));
            float xn[6];
            for (int i = 0; i < 6; i++)
                xn[i] = c2 ? xf[i] : (float)((double)xf[i] - x0[i]);
            for (int i = 0; i < 6; i++) sx[i] = xn[i];
            sconv = c2 ? 1.f : 0.f;
            if (!convold) scost = (float)new_cost;

            float T[16];
            exp_se3_f32(xn, T);
            sR[0] = T[0]; sR[1] = T[1]; sR[2] = T[2];
            sR[3] = T[4]; sR[4] = T[5]; sR[5] = T[6];
            sR[6] = T[8]; sR[7] = T[9]; sR[8] = T[10];
            st_[0] = T[3]; st_[1] = T[7]; st_[2] = T[11];

            if (it == 19 && bid == 0) {
                for (int i = 0; i < 16; i++) out[i] = T[i];
                out[16] = scost;
            }
        }
        __syncthreads();   // new LDS state visible to whole block before next iter
    }
}

extern "C" void kernel_launch(void* const* d_in, const int* in_sizes, int n_in,
                              void* d_out, int out_size, void* d_ws, size_t ws_size,
                              hipStream_t stream) {
    const float* depth_ref      = (const float*)d_in[0];
    const float* normals_ref    = (const float*)d_in[1];
    const float* gray_ref       = (const float*)d_in[2];
    const float* gray_target    = (const float*)d_in[3];
    const float* points_target  = (const float*)d_in[4];
    const float* normals_target = (const float*)d_in[5];
    const float* K              = (const float*)d_in[6];
    float* ws  = (float*)d_ws;
    float* out = (float*)d_out;

    // zero the barrier state (captured into the graph; replays deterministically)
    hipMemsetAsync(d_ws, 0, 256, stream);

    bool big = ws_size >= (size_t)WS_BIG_END * sizeof(float);
    if (big) {
        hipLaunchKernelGGL((fused_icp<1>), dim3(MB), dim3(TPB), 0, stream,
                           depth_ref, normals_ref, gray_ref, gray_target,
                           points_target, normals_target, K, ws, out);
    } else {
        hipLaunchKernelGGL((fused_icp<0>), dim3(MB), dim3(TPB), 0, stream,
                           depth_ref, normals_ref, gray_ref, gray_target,
                           points_target, normals_target, K, ws, out);
    }
}

// Round 6
// 782.972 us; speedup vs baseline: 2.1915x; 2.1915x over previous
//
#include <hip/hip_runtime.h>
#include <math.h>

#define HH 480
#define WW 640
#define NPIX (HH*WW)
#define NACC 29           // 21 (A upper tri) + 6 (b) + 1 (sum r_icp^2) + 1 (sum r_rgb^2)
#define TPB 256
#define PXPT 3
#define MB 400            // 400 * 256 * 3 = 307200 = NPIX, exact
#define NLEAF 8

// d_ws float-index layout:
//   [0..511]       barrier ints: [0]=generation, [8]=root arrive, [32+32*i]=leaf i
//                  (zeroed by hipMemsetAsync(2048) each launch)
//   [WS_P0 ..)     partials buf A (transposed [q][block]), NACC*MB floats  (sc1-only!)
//   [WS_P1 ..)     partials buf B                                          (sc1-only!)
//   big variant only:
//   [WS_G4 ..)     float4 per pixel: (gray, gx, gy, 0)
//   [WS_PN ..)     2x float4 per pixel: (qx,qy,qz,nqx),(nqy,nqz,0,0)
#define WS_P0 512
#define WS_P1 (WS_P0 + NACC*MB)            // 12112
#define WS_G4 23808                        // 16-float aligned
#define WS_PN (WS_G4 + NPIX*4)             // 1252608
#define WS_BIG_END (WS_PN + NPIX*8)        // 3710208 floats (~14.84 MB)

__device__ __forceinline__ float gradu(const float* g, int v, int u) {
    const float* row = g + v * WW;
    if (u == 0)      return row[1] - row[0];
    if (u == WW - 1) return row[WW - 1] - row[WW - 2];
    return 0.5f * (row[u + 1] - row[u - 1]);
}
__device__ __forceinline__ float gradv(const float* g, int v, int u) {
    if (v == 0)      return g[WW + u] - g[u];
    if (v == HH - 1) return g[(HH - 1) * WW + u] - g[(HH - 2) * WW + u];
    return 0.5f * (g[(v + 1) * WW + u] - g[(v - 1) * WW + u]);
}

__device__ void exp_se3_f32(const float* xi, float* T) {
    float v0 = xi[0], v1 = xi[1], v2 = xi[2];
    float w0 = xi[3], w1 = xi[4], w2 = xi[5];
    float th2 = w0 * w0 + w1 * w1 + w2 * w2;
    float th = sqrtf(th2);
    bool small = th < 1e-8f;
    float ths = small ? 1.0f : th;
    float A = small ? (1.0f - th2 / 6.0f) : (sinf(ths) / ths);
    float B = small ? (0.5f - th2 / 24.0f) : ((1.0f - cosf(ths)) / (ths * ths));
    float C = small ? (1.0f / 6.0f - th2 / 120.0f) : ((ths - sinf(ths)) / (ths * ths * ths));
    float Wx[9] = { 0.f, -w2,  w1,
                    w2,  0.f, -w0,
                   -w1,  w0,  0.f };
    float W2[9];
    #pragma unroll
    for (int i = 0; i < 3; i++)
        #pragma unroll
        for (int j = 0; j < 3; j++) {
            float s = 0.f;
            #pragma unroll
            for (int k = 0; k < 3; k++) s += Wx[i * 3 + k] * Wx[k * 3 + j];
            W2[i * 3 + j] = s;
        }
    float R[9], V[9];
    #pragma unroll
    for (int i = 0; i < 9; i++) {
        float id = (i == 0 || i == 4 || i == 8) ? 1.0f : 0.0f;
        R[i] = id + A * Wx[i] + B * W2[i];
        V[i] = id + B * Wx[i] + C * W2[i];
    }
    float t0 = V[0] * v0 + V[1] * v1 + V[2] * v2;
    float t1 = V[3] * v0 + V[4] * v1 + V[5] * v2;
    float t2 = V[6] * v0 + V[7] * v1 + V[8] * v2;
    T[0] = R[0]; T[1] = R[1]; T[2]  = R[2]; T[3]  = t0;
    T[4] = R[3]; T[5] = R[4]; T[6]  = R[5]; T[7]  = t1;
    T[8] = R[6]; T[9] = R[7]; T[10] = R[8]; T[11] = t2;
    T[12] = 0.f; T[13] = 0.f; T[14] = 0.f; T[15] = 1.f;
}

__device__ __forceinline__ void accum_point(float* acc, const float* J, float r, float w, int costslot) {
    int k = 0;
    #pragma unroll
    for (int i = 0; i < 6; i++) {
        #pragma unroll
        for (int j = i; j < 6; j++) { acc[k] += w * (J[i] * J[j]); k++; }
        acc[21 + i] += w * (J[i] * r);
    }
    acc[costslot] += r * r;
}

// Cache-preserving grid barrier. All ops are RELAXED agent-scope (bypass L2,
// complete at the coherent point) -> no buffer_inv / buffer_wbl2, L2 contents
// survive. Expected generation is tracked in a register (no pre-read race).
// Requires all blocks co-resident (grid=400 <= 512 @ __launch_bounds__(256,2)).
__device__ __forceinline__ void grid_barrier(int* bar, int bid, int* bar_count) {
    __syncthreads();   // drains each wave's outstanding stores before tid0 arrives
    if (threadIdx.x == 0) {
        int target = ++(*bar_count);
        int leaf = bid & (NLEAF - 1);
        int* lc = bar + 32 + 32 * leaf;
        const int gsz = MB / NLEAF;            // 50
        int a = __hip_atomic_fetch_add(lc, 1, __ATOMIC_RELAXED, __HIP_MEMORY_SCOPE_AGENT);
        if (((a + 1) % gsz) == 0) {
            int r = __hip_atomic_fetch_add(bar + 8, 1, __ATOMIC_RELAXED, __HIP_MEMORY_SCOPE_AGENT);
            if (((r + 1) % NLEAF) == 0) {
                __hip_atomic_fetch_add(bar, 1, __ATOMIC_RELAXED, __HIP_MEMORY_SCOPE_AGENT);
            }
        }
        while (__hip_atomic_load(bar, __ATOMIC_RELAXED, __HIP_MEMORY_SCOPE_AGENT) < target) {
            __builtin_amdgcn_s_sleep(4);
        }
    }
    __syncthreads();
}

template <int PACKED>
__global__ __launch_bounds__(TPB, 2) void fused_icp(
    const float* __restrict__ depth_ref,
    const float* __restrict__ normals_ref,
    const float* __restrict__ gray_ref,
    const float* __restrict__ gray_target,
    const float* __restrict__ points_target,
    const float* __restrict__ normals_target,
    const float* __restrict__ K,
    float* __restrict__ ws,
    float* __restrict__ out)
{
    const int tid = threadIdx.x;
    const int bid = blockIdx.x;
    const float fx = K[0], cx = K[2], fy = K[4], cy = K[5];
    int* bar = (int*)ws;
    int bar_count = 0;
    float4* g4 = (float4*)(ws + WS_G4);
    float4* pn = (float4*)(ws + WS_PN);

    // ---- one-time packed-texture precompute (big variant only) ----
    if (PACKED) {
        int base = bid * (TPB * PXPT) + tid;
        #pragma unroll
        for (int k = 0; k < PXPT; k++) {
            int p = base + k * TPB;
            int v = p / WW, u = p - v * WW;
            float4 c;
            c.x = gray_target[p];
            c.y = gradu(gray_target, v, u);
            c.z = gradv(gray_target, v, u);
            c.w = 0.f;
            g4[p] = c;
            float4 a, b;
            a.x = points_target[3 * p];
            a.y = points_target[3 * p + 1];
            a.z = points_target[3 * p + 2];
            a.w = normals_target[3 * p];
            b.x = normals_target[3 * p + 1];
            b.y = normals_target[3 * p + 2];
            b.z = 0.f; b.w = 0.f;
            pn[2 * p] = a;
            pn[2 * p + 1] = b;
        }
        __threadfence();   // ONE-TIME wbl2: push plain-stored textures to coherent point
        grid_barrier(bar, bid, &bar_count);
    }

    // ---- per-block pose state in LDS (identical across blocks every iter) ----
    __shared__ float sR[9], st_[3], sx[6];
    __shared__ float sconv, scost;
    __shared__ float lds[4][NACC];
    __shared__ double part8[NACC * 8];
    __shared__ double sums[NACC];

    if (tid == 0) {
        sR[0] = 1.f; sR[1] = 0.f; sR[2] = 0.f;
        sR[3] = 0.f; sR[4] = 1.f; sR[5] = 0.f;
        sR[6] = 0.f; sR[7] = 0.f; sR[8] = 1.f;
        st_[0] = 0.f; st_[1] = 0.f; st_[2] = 0.f;
        #pragma unroll
        for (int i = 0; i < 6; i++) sx[i] = 0.f;
        sconv = 0.f; scost = 0.f;
    }
    __syncthreads();

    for (int it = 0; it < 20; ++it) {
        const float R00 = sR[0], R01 = sR[1], R02 = sR[2];
        const float R10 = sR[3], R11 = sR[4], R12 = sR[5];
        const float R20 = sR[6], R21 = sR[7], R22 = sR[8];
        const float t0 = st_[0], t1 = st_[1], t2 = st_[2];

        float acc[NACC];
        #pragma unroll
        for (int i = 0; i < NACC; i++) acc[i] = 0.f;

        int pbase = bid * (TPB * PXPT) + tid;
        #pragma unroll
        for (int kk = 0; kk < PXPT; kk++) {
            int p = pbase + kk * TPB;
            int vv = p / WW;
            int uu = p - vv * WW;

            float Z = depth_ref[p];
            float Px = ((float)uu - cx) / fx * Z;
            float Py = ((float)vv - cy) / fy * Z;
            float Pz = Z;
            float Ptx = R00 * Px + R01 * Py + R02 * Pz + t0;
            float Pty = R10 * Px + R11 * Py + R12 * Pz + t1;
            float Ptz = R20 * Px + R21 * Py + R22 * Pz + t2;
            bool okz = Ptz > 1e-6f;
            float Zs = okz ? Ptz : 1.0f;
            float u = fx * Ptx / Zs + cx;
            float v = fy * Pty / Zs + cy;
            bool inb = okz && (u >= 0.f) && (u <= (float)(WW - 1)) && (v >= 0.f) && (v <= (float)(HH - 1));
            if (!inb) continue;

            // ---- ICP term ----
            int ui = (int)rintf(u); ui = ui < 0 ? 0 : (ui > WW - 1 ? WW - 1 : ui);
            int vi = (int)rintf(v); vi = vi < 0 ? 0 : (vi > HH - 1 ? HH - 1 : vi);
            int ti = vi * WW + ui;
            float qx, qy, qz, nqx, nqy, nqz;
            if (PACKED) {
                float4 a = pn[2 * ti], b = pn[2 * ti + 1];
                qx = a.x; qy = a.y; qz = a.z; nqx = a.w; nqy = b.x; nqz = b.y;
            } else {
                qx = points_target[3 * ti]; qy = points_target[3 * ti + 1]; qz = points_target[3 * ti + 2];
                nqx = normals_target[3 * ti]; nqy = normals_target[3 * ti + 1]; nqz = normals_target[3 * ti + 2];
            }
            float dx = Ptx - qx, dy = Pty - qy, dz = Ptz - qz;
            float nr0 = normals_ref[3 * p], nr1 = normals_ref[3 * p + 1], nr2 = normals_ref[3 * p + 2];
            float nrx = R00 * nr0 + R01 * nr1 + R02 * nr2;
            float nry = R10 * nr0 + R11 * nr1 + R12 * nr2;
            float nrz = R20 * nr0 + R21 * nr1 + R22 * nr2;
            const float DIST2 = (float)((200.0 / 15.0) * (200.0 / 15.0));
            if ((dx * dx + dy * dy + dz * dz) < DIST2 &&
                (nrx * nqx + nry * nqy + nrz * nqz) > 0.94f) {
                float r = nqx * dx + nqy * dy + nqz * dz;
                float J[6] = { nqx, nqy, nqz,
                               Pty * nqz - Ptz * nqy,
                               Ptz * nqx - Ptx * nqz,
                               Ptx * nqy - Pty * nqx };
                accum_point(acc, J, r, 10.0f, 27);
            }
            // ---- RGB (photometric) term ----
            float u0f = floorf(u), v0f = floorf(v);
            float du = u - u0f, dv = v - v0f;
            int u0 = (int)u0f; u0 = u0 < 0 ? 0 : (u0 > WW - 1 ? WW - 1 : u0);
            int u1 = (u0 + 1 > WW - 1) ? WW - 1 : u0 + 1;
            int v0 = (int)v0f; v0 = v0 < 0 ? 0 : (v0 > HH - 1 ? HH - 1 : v0);
            int v1 = (v0 + 1 > HH - 1) ? HH - 1 : v0 + 1;
            int i00 = v0 * WW + u0, i01 = v0 * WW + u1, i10 = v1 * WW + u0, i11 = v1 * WW + u1;
            float I00, I01, I10, I11, gx00, gx01, gx10, gx11, gy00, gy01, gy10, gy11;
            if (PACKED) {
                float4 c00 = g4[i00], c01 = g4[i01], c10 = g4[i10], c11 = g4[i11];
                I00 = c00.x; gx00 = c00.y; gy00 = c00.z;
                I01 = c01.x; gx01 = c01.y; gy01 = c01.z;
                I10 = c10.x; gx10 = c10.y; gy10 = c10.z;
                I11 = c11.x; gx11 = c11.y; gy11 = c11.z;
            } else {
                const float* g = gray_target;
                I00 = g[i00]; I01 = g[i01]; I10 = g[i10]; I11 = g[i11];
                gx00 = gradu(g, v0, u0); gx01 = gradu(g, v0, u1);
                gx10 = gradu(g, v1, u0); gx11 = gradu(g, v1, u1);
                gy00 = gradv(g, v0, u0); gy01 = gradv(g, v0, u1);
                gy10 = gradv(g, v1, u0); gy11 = gradv(g, v1, u1);
            }
            float It  = (I00 * (1.f - du) + I01 * du) * (1.f - dv) + (I10 * (1.f - du) + I11 * du) * dv;
            float gxs = (gx00 * (1.f - du) + gx01 * du) * (1.f - dv) + (gx10 * (1.f - du) + gx11 * du) * dv;
            float gys = (gy00 * (1.f - du) + gy01 * du) * (1.f - dv) + (gy10 * (1.f - du) + gy11 * du) * dv;
            float rr = It - gray_ref[p];
            float gpx = gxs * fx / Zs;
            float gpy = gys * fy / Zs;
            float gpz = -(gxs * fx * Ptx + gys * fy * Pty) / (Zs * Zs);
            float J[6] = { gpx, gpy, gpz,
                           Pty * gpz - Ptz * gpy,
                           Ptz * gpx - Ptx * gpz,
                           Ptx * gpy - Pty * gpx };
            accum_point(acc, J, rr, 1.0f, 28);
        }

        // ---- deterministic in-block reduction: wave shuffle -> LDS ----
        #pragma unroll
        for (int q = 0; q < NACC; q++) {
            float vq = acc[q];
            #pragma unroll
            for (int off = 32; off >= 1; off >>= 1) vq += __shfl_xor(vq, off);
            acc[q] = vq;
        }
        int wave = tid >> 6;
        int lane = tid & 63;
        __syncthreads();   // protect lds[][] reuse across iterations
        if (lane == 0) {
            #pragma unroll
            for (int q = 0; q < NACC; q++) lds[wave][q] = acc[q];
        }
        __syncthreads();
        float* pbuf = ws + ((it & 1) ? WS_P1 : WS_P0);
        if (tid < NACC) {
            int q = tid;
            float s = lds[0][q] + lds[1][q] + lds[2][q] + lds[3][q];
            // agent-scope store: completes at coherent point, never invalidates L2
            __hip_atomic_store(&pbuf[q * MB + bid], s, __ATOMIC_RELAXED, __HIP_MEMORY_SCOPE_AGENT);
        }
        grid_barrier(bar, bid, &bar_count);

        // ---- every block redundantly reduces all partials + solves (f64) ----
        if (tid < NACC * 8) {
            int q = tid >> 3, s = tid & 7;
            const int CH = MB / 8;            // 50 (NOT divisible by 4 -> remainder!)
            int lo = s * CH, hi = lo + CH;
            float* row = pbuf + q * MB;
            double a0 = 0.0, a1 = 0.0, a2 = 0.0, a3 = 0.0;
            int i = lo;
            for (; i + 4 <= hi; i += 4) {
                a0 += (double)__hip_atomic_load(&row[i],     __ATOMIC_RELAXED, __HIP_MEMORY_SCOPE_AGENT);
                a1 += (double)__hip_atomic_load(&row[i + 1], __ATOMIC_RELAXED, __HIP_MEMORY_SCOPE_AGENT);
                a2 += (double)__hip_atomic_load(&row[i + 2], __ATOMIC_RELAXED, __HIP_MEMORY_SCOPE_AGENT);
                a3 += (double)__hip_atomic_load(&row[i + 3], __ATOMIC_RELAXED, __HIP_MEMORY_SCOPE_AGENT);
            }
            for (; i < hi; i++)   // CH=50: last 2 elements of each chunk
                a0 += (double)__hip_atomic_load(&row[i], __ATOMIC_RELAXED, __HIP_MEMORY_SCOPE_AGENT);
            part8[tid] = ((a0 + a1) + (a2 + a3));
        }
        __syncthreads();
        if (tid < NACC) {
            double sm = 0.0;
            #pragma unroll
            for (int s = 0; s < 8; s++) sm += part8[tid * 8 + s];
            sums[tid] = sm;
        }
        __syncthreads();
        if (tid == 0) {
            double M[6][7];
            int k = 0;
            for (int i = 0; i < 6; i++)
                for (int j = i; j < 6; j++) { M[i][j] = sums[k]; M[j][i] = sums[k]; k++; }
            for (int i = 0; i < 6; i++) { M[i][6] = sums[21 + i]; M[i][i] += 1e-9; }
            double new_cost = 10.0 * sums[27] / (double)NPIX + sums[28] / (double)NPIX;

            for (int c = 0; c < 6; c++) {
                int piv = c; double mx = fabs(M[c][c]);
                for (int r2 = c + 1; r2 < 6; r2++) {
                    double a = fabs(M[r2][c]);
                    if (a > mx) { mx = a; piv = r2; }
                }
                if (piv != c)
                    for (int j2 = 0; j2 < 7; j2++) { double tmp = M[c][j2]; M[c][j2] = M[piv][j2]; M[piv][j2] = tmp; }
                double inv = 1.0 / M[c][c];
                for (int r2 = c + 1; r2 < 6; r2++) {
                    double f = M[r2][c] * inv;
                    for (int j2 = c; j2 < 7; j2++) M[r2][j2] -= f * M[c][j2];
                }
            }
            double x0[6];
            for (int i = 5; i >= 0; i--) {
                double s = M[i][6];
                for (int j = i + 1; j < 6; j++) s -= M[i][j] * x0[j];
                x0[i] = s / M[i][i];
            }

            double nx0 = 0.0, nx = 0.0;
            float xf[6];
            for (int i = 0; i < 6; i++) {
                xf[i] = sx[i];
                nx0 += x0[i] * x0[i];
                nx  += (double)xf[i] * (double)xf[i];
            }
            nx0 = sqrt(nx0); nx = sqrt(nx);
            bool convold = (sconv != 0.f);
            bool c2 = convold || (new_cost < 1e-3) || (nx0 < 1e-8 * (1e-8 + nx));
            float xn[6];
            for (int i = 0; i < 6; i++)
                xn[i] = c2 ? xf[i] : (float)((double)xf[i] - x0[i]);
            for (int i = 0; i < 6; i++) sx[i] = xn[i];
            sconv = c2 ? 1.f : 0.f;
            if (!convold) scost = (float)new_cost;

            float T[16];
            exp_se3_f32(xn, T);
            sR[0] = T[0]; sR[1] = T[1]; sR[2] = T[2];
            sR[3] = T[4]; sR[4] = T[5]; sR[5] = T[6];
            sR[6] = T[8]; sR[7] = T[9]; sR[8] = T[10];
            st_[0] = T[3]; st_[1] = T[7]; st_[2] = T[11];

            if (it == 19 && bid == 0) {
                for (int i = 0; i < 16; i++) out[i] = T[i];
                out[16] = scost;
            }
        }
        __syncthreads();   // new LDS state visible to whole block before next iter
    }
}

extern "C" void kernel_launch(void* const* d_in, const int* in_sizes, int n_in,
                              void* d_out, int out_size, void* d_ws, size_t ws_size,
                              hipStream_t stream) {
    const float* depth_ref      = (const float*)d_in[0];
    const float* normals_ref    = (const float*)d_in[1];
    const float* gray_ref       = (const float*)d_in[2];
    const float* gray_target    = (const float*)d_in[3];
    const float* points_target  = (const float*)d_in[4];
    const float* normals_target = (const float*)d_in[5];
    const float* K              = (const float*)d_in[6];
    float* ws  = (float*)d_ws;
    float* out = (float*)d_out;

    // zero the barrier state (captured into the graph; replays deterministically)
    hipMemsetAsync(d_ws, 0, 2048, stream);

    bool big = ws_size >= (size_t)WS_BIG_END * sizeof(float);
    if (big) {
        hipLaunchKernelGGL((fused_icp<1>), dim3(MB), dim3(TPB), 0, stream,
                           depth_ref, normals_ref, gray_ref, gray_target,
                           points_target, normals_target, K, ws, out);
    } else {
        hipLaunchKernelGGL((fused_icp<0>), dim3(MB), dim3(TPB), 0, stream,
                           depth_ref, normals_ref, gray_ref, gray_target,
                           points_target, normals_target, K, ws, out);
    }
}

// Round 7
// 538.262 us; speedup vs baseline: 3.1878x; 1.4546x over previous
//
#include <hip/hip_runtime.h>
#include <math.h>

#define HH 480
#define WW 640
#define NPIX (HH*WW)
#define NACC 29           // 21 (A upper tri) + 6 (b) + 1 (sum r_icp^2) + 1 (sum r_rgb^2)
#define TPB 256
#define PXPT 3
#define MB 400            // 400 * 256 * 3 = 307200 = NPIX, exact
#define NLEAF 16
#define GSZ (MB/NLEAF)    // 25

// d_ws layout (float indices; first 2048 BYTES zeroed by hipMemsetAsync each launch):
//   int[0]            epoch (written ONLY by block0)
//   int[16]           root arrive counter
//   int[128+16*i]     leaf arrive counter i, i<16  (separate 64B lines)
//   float[64..76)     pose packet: R(9), t(3)      (sc1-only)
//   [WS_P0 ..)        partials buf A [q][block], NACC*MB floats (sc1-only)
//   [WS_P1 ..)        partials buf B
//   PACKED only:
//   [WS_G4 ..)        float4/px: (grayT, gx, gy, 0)
//   [WS_NR ..)        float4/px: (nr0, nr1, nr2, depth_ref)
//   [WS_PZ ..)        float4/px: (ptz, nq0, nq1, nq2)
#define WS_PKT 64
#define WS_P0 512
#define WS_P1 (WS_P0 + NACC*MB)            // 12112
#define WS_G4 23808                        // 16B-aligned
#define WS_NR (WS_G4 + NPIX*4)
#define WS_PZ (WS_NR + NPIX*4)
#define WS_BIG_END (WS_PZ + NPIX*4)        // 3710208 floats (~14.84 MB) — same gate as r6

__device__ __forceinline__ int ld_i_sc1(const int* p) {
    return __hip_atomic_load(p, __ATOMIC_RELAXED, __HIP_MEMORY_SCOPE_AGENT);
}
__device__ __forceinline__ float ld_f_sc1(const float* p) {
    return __hip_atomic_load(p, __ATOMIC_RELAXED, __HIP_MEMORY_SCOPE_AGENT);
}
__device__ __forceinline__ void st_f_sc1(float* p, float v) {
    __hip_atomic_store(p, v, __ATOMIC_RELAXED, __HIP_MEMORY_SCOPE_AGENT);
}
// arrive: leaf add; leaf-closer adds to root. Called by tid0 after __syncthreads
// (which drains the wave's outstanding sc1 partial stores -> partials are at the
// coherent point before the arrive RMW is issued).
__device__ __forceinline__ void arrive(int* bar, int bid) {
    int* lc = bar + 128 + 16 * (bid & (NLEAF - 1));
    int a = __hip_atomic_fetch_add(lc, 1, __ATOMIC_RELAXED, __HIP_MEMORY_SCOPE_AGENT);
    if (((a + 1) % GSZ) == 0)
        __hip_atomic_fetch_add(bar + 16, 1, __ATOMIC_RELAXED, __HIP_MEMORY_SCOPE_AGENT);
}

__device__ __forceinline__ float gradu(const float* g, int v, int u) {
    const float* row = g + v * WW;
    if (u == 0)      return row[1] - row[0];
    if (u == WW - 1) return row[WW - 1] - row[WW - 2];
    return 0.5f * (row[u + 1] - row[u - 1]);
}
__device__ __forceinline__ float gradv(const float* g, int v, int u) {
    if (v == 0)      return g[WW + u] - g[u];
    if (v == HH - 1) return g[(HH - 1) * WW + u] - g[(HH - 2) * WW + u];
    return 0.5f * (g[(v + 1) * WW + u] - g[(v - 1) * WW + u]);
}

__device__ void exp_se3_f32(const float* xi, float* T) {
    float v0 = xi[0], v1 = xi[1], v2 = xi[2];
    float w0 = xi[3], w1 = xi[4], w2 = xi[5];
    float th2 = w0 * w0 + w1 * w1 + w2 * w2;
    float th = sqrtf(th2);
    bool small = th < 1e-8f;
    float ths = small ? 1.0f : th;
    float A = small ? (1.0f - th2 / 6.0f) : (sinf(ths) / ths);
    float B = small ? (0.5f - th2 / 24.0f) : ((1.0f - cosf(ths)) / (ths * ths));
    float C = small ? (1.0f / 6.0f - th2 / 120.0f) : ((ths - sinf(ths)) / (ths * ths * ths));
    float Wx[9] = { 0.f, -w2,  w1,
                    w2,  0.f, -w0,
                   -w1,  w0,  0.f };
    float W2[9];
    #pragma unroll
    for (int i = 0; i < 3; i++)
        #pragma unroll
        for (int j = 0; j < 3; j++) {
            float s = 0.f;
            #pragma unroll
            for (int k = 0; k < 3; k++) s += Wx[i * 3 + k] * Wx[k * 3 + j];
            W2[i * 3 + j] = s;
        }
    float R[9], V[9];
    #pragma unroll
    for (int i = 0; i < 9; i++) {
        float id = (i == 0 || i == 4 || i == 8) ? 1.0f : 0.0f;
        R[i] = id + A * Wx[i] + B * W2[i];
        V[i] = id + B * Wx[i] + C * W2[i];
    }
    float t0 = V[0] * v0 + V[1] * v1 + V[2] * v2;
    float t1 = V[3] * v0 + V[4] * v1 + V[5] * v2;
    float t2 = V[6] * v0 + V[7] * v1 + V[8] * v2;
    T[0] = R[0]; T[1] = R[1]; T[2]  = R[2]; T[3]  = t0;
    T[4] = R[3]; T[5] = R[4]; T[6]  = R[5]; T[7]  = t1;
    T[8] = R[6]; T[9] = R[7]; T[10] = R[8]; T[11] = t2;
    T[12] = 0.f; T[13] = 0.f; T[14] = 0.f; T[15] = 1.f;
}

__device__ __forceinline__ void accum_point(float* acc, const float* J, float r, float w, int costslot) {
    int k = 0;
    #pragma unroll
    for (int i = 0; i < 6; i++) {
        #pragma unroll
        for (int j = i; j < 6; j++) { acc[k] += w * (J[i] * J[j]); k++; }
        acc[21 + i] += w * (J[i] * r);
    }
    acc[costslot] += r * r;
}

template <int PACKED>
__global__ __launch_bounds__(TPB, 2) void fused_icp(
    const float* __restrict__ depth_ref,
    const float* __restrict__ normals_ref,
    const float* __restrict__ gray_ref,
    const float* __restrict__ gray_target,
    const float* __restrict__ points_target,
    const float* __restrict__ normals_target,
    const float* __restrict__ K,
    float* __restrict__ ws,
    float* __restrict__ out)
{
    const int tid = threadIdx.x;
    const int bid = blockIdx.x;
    const float fx = K[0], cx = K[2], fy = K[4], cy = K[5];
    int* bar = (int*)ws;
    float* pkt = ws + WS_PKT;
    int sync_no = 0;
    float4* g4  = (float4*)(ws + WS_G4);
    float4* nr4 = (float4*)(ws + WS_NR);
    float4* pz4 = (float4*)(ws + WS_PZ);

    // ---- one-time packed-texture precompute (PACKED only) ----
    if (PACKED) {
        int base = bid * (TPB * PXPT) + tid;
        #pragma unroll
        for (int k = 0; k < PXPT; k++) {
            int p = base + k * TPB;
            int v = p / WW, u = p - v * WW;
            float4 c;
            c.x = gray_target[p];
            c.y = gradu(gray_target, v, u);
            c.z = gradv(gray_target, v, u);
            c.w = 0.f;
            g4[p] = c;
            float4 n;
            n.x = normals_ref[3 * p];
            n.y = normals_ref[3 * p + 1];
            n.z = normals_ref[3 * p + 2];
            n.w = depth_ref[p];
            nr4[p] = n;
            float4 z;
            z.x = points_target[3 * p + 2];
            z.y = normals_target[3 * p];
            z.z = normals_target[3 * p + 1];
            z.w = normals_target[3 * p + 2];
            pz4[p] = z;
        }
        __threadfence();   // one-time: push plain-stored textures to the coherent point
        __syncthreads();
        if (tid == 0) arrive(bar, bid);
        sync_no++;
        if (bid == 0 && tid == 0) {
            while (ld_i_sc1(bar + 16) < NLEAF * sync_no) __builtin_amdgcn_s_sleep(1);
            asm volatile("s_waitcnt vmcnt(0)" ::: "memory");
            __hip_atomic_store(bar, sync_no, __ATOMIC_RELAXED, __HIP_MEMORY_SCOPE_AGENT);
        }
        if (tid == 0) {
            while (ld_i_sc1(bar) < sync_no) __builtin_amdgcn_s_sleep(4);
        }
        __syncthreads();
    }

    // ---- pose mirror (all blocks) + solver state (block0 only) ----
    __shared__ float spose[12];             // R row-major, t
    __shared__ float sx[6];
    __shared__ float sconv, scost;
    __shared__ float lds[4][NACC];
    __shared__ double part8[NACC * 8];
    __shared__ double sums[NACC];

    if (tid == 0) {
        spose[0] = 1.f; spose[1] = 0.f; spose[2] = 0.f;
        spose[3] = 0.f; spose[4] = 1.f; spose[5] = 0.f;
        spose[6] = 0.f; spose[7] = 0.f; spose[8] = 1.f;
        spose[9] = 0.f; spose[10] = 0.f; spose[11] = 0.f;
        #pragma unroll
        for (int i = 0; i < 6; i++) sx[i] = 0.f;
        sconv = 0.f; scost = 0.f;
    }
    __syncthreads();

    for (int it = 0; it < 20; ++it) {
        const float R00 = spose[0], R01 = spose[1], R02 = spose[2];
        const float R10 = spose[3], R11 = spose[4], R12 = spose[5];
        const float R20 = spose[6], R21 = spose[7], R22 = spose[8];
        const float t0 = spose[9], t1 = spose[10], t2 = spose[11];

        float acc[NACC];
        #pragma unroll
        for (int i = 0; i < NACC; i++) acc[i] = 0.f;

        int pbase = bid * (TPB * PXPT) + tid;
        #pragma unroll
        for (int kk = 0; kk < PXPT; kk++) {
            int p = pbase + kk * TPB;
            int vv = p / WW;
            int uu = p - vv * WW;

            float nr0, nr1, nr2, Z;
            if (PACKED) {
                float4 n = nr4[p];
                nr0 = n.x; nr1 = n.y; nr2 = n.z; Z = n.w;
            } else {
                Z = depth_ref[p];
                nr0 = normals_ref[3 * p]; nr1 = normals_ref[3 * p + 1]; nr2 = normals_ref[3 * p + 2];
            }
            float Px = ((float)uu - cx) / fx * Z;
            float Py = ((float)vv - cy) / fy * Z;
            float Pz = Z;
            float Ptx = R00 * Px + R01 * Py + R02 * Pz + t0;
            float Pty = R10 * Px + R11 * Py + R12 * Pz + t1;
            float Ptz = R20 * Px + R21 * Py + R22 * Pz + t2;
            bool okz = Ptz > 1e-6f;
            float Zs = okz ? Ptz : 1.0f;
            float u = fx * Ptx / Zs + cx;
            float v = fy * Pty / Zs + cy;
            bool inb = okz && (u >= 0.f) && (u <= (float)(WW - 1)) && (v >= 0.f) && (v <= (float)(HH - 1));
            if (!inb) continue;

            // ---- ICP term ----
            int ui = (int)rintf(u); ui = ui < 0 ? 0 : (ui > WW - 1 ? WW - 1 : ui);
            int vi = (int)rintf(v); vi = vi < 0 ? 0 : (vi > HH - 1 ? HH - 1 : vi);
            int ti = vi * WW + ui;
            float qx, qy, qz, nqx, nqy, nqz;
            if (PACKED) {
                float4 z = pz4[ti];
                qz = z.x; nqx = z.y; nqy = z.z; nqz = z.w;
                // bitwise-identical recompute of setup's (uu-cx)/fx*Z chain
                qx = (((float)ui) - cx) / fx * qz;
                qy = (((float)vi) - cy) / fy * qz;
            } else {
                qx = points_target[3 * ti]; qy = points_target[3 * ti + 1]; qz = points_target[3 * ti + 2];
                nqx = normals_target[3 * ti]; nqy = normals_target[3 * ti + 1]; nqz = normals_target[3 * ti + 2];
            }
            float dx = Ptx - qx, dy = Pty - qy, dz = Ptz - qz;
            float nrx = R00 * nr0 + R01 * nr1 + R02 * nr2;
            float nry = R10 * nr0 + R11 * nr1 + R12 * nr2;
            float nrz = R20 * nr0 + R21 * nr1 + R22 * nr2;
            const float DIST2 = (float)((200.0 / 15.0) * (200.0 / 15.0));
            if ((dx * dx + dy * dy + dz * dz) < DIST2 &&
                (nrx * nqx + nry * nqy + nrz * nqz) > 0.94f) {
                float r = nqx * dx + nqy * dy + nqz * dz;
                float J[6] = { nqx, nqy, nqz,
                               Pty * nqz - Ptz * nqy,
                               Ptz * nqx - Ptx * nqz,
                               Ptx * nqy - Pty * nqx };
                accum_point(acc, J, r, 10.0f, 27);
            }
            // ---- RGB (photometric) term ----
            float u0f = floorf(u), v0f = floorf(v);
            float du = u - u0f, dv = v - v0f;
            int u0 = (int)u0f; u0 = u0 < 0 ? 0 : (u0 > WW - 1 ? WW - 1 : u0);
            int u1 = (u0 + 1 > WW - 1) ? WW - 1 : u0 + 1;
            int v0 = (int)v0f; v0 = v0 < 0 ? 0 : (v0 > HH - 1 ? HH - 1 : v0);
            int v1 = (v0 + 1 > HH - 1) ? HH - 1 : v0 + 1;
            int i00 = v0 * WW + u0, i01 = v0 * WW + u1, i10 = v1 * WW + u0, i11 = v1 * WW + u1;
            float I00, I01, I10, I11, gx00, gx01, gx10, gx11, gy00, gy01, gy10, gy11;
            if (PACKED) {
                float4 c00 = g4[i00], c01 = g4[i01], c10 = g4[i10], c11 = g4[i11];
                I00 = c00.x; gx00 = c00.y; gy00 = c00.z;
                I01 = c01.x; gx01 = c01.y; gy01 = c01.z;
                I10 = c10.x; gx10 = c10.y; gy10 = c10.z;
                I11 = c11.x; gx11 = c11.y; gy11 = c11.z;
            } else {
                const float* g = gray_target;
                I00 = g[i00]; I01 = g[i01]; I10 = g[i10]; I11 = g[i11];
                gx00 = gradu(g, v0, u0); gx01 = gradu(g, v0, u1);
                gx10 = gradu(g, v1, u0); gx11 = gradu(g, v1, u1);
                gy00 = gradv(g, v0, u0); gy01 = gradv(g, v0, u1);
                gy10 = gradv(g, v1, u0); gy11 = gradv(g, v1, u1);
            }
            float It  = (I00 * (1.f - du) + I01 * du) * (1.f - dv) + (I10 * (1.f - du) + I11 * du) * dv;
            float gxs = (gx00 * (1.f - du) + gx01 * du) * (1.f - dv) + (gx10 * (1.f - du) + gx11 * du) * dv;
            float gys = (gy00 * (1.f - du) + gy01 * du) * (1.f - dv) + (gy10 * (1.f - du) + gy11 * du) * dv;
            float rr = It - gray_ref[p];
            float gpx = gxs * fx / Zs;
            float gpy = gys * fy / Zs;
            float gpz = -(gxs * fx * Ptx + gys * fy * Pty) / (Zs * Zs);
            float J[6] = { gpx, gpy, gpz,
                           Pty * gpz - Ptz * gpy,
                           Ptz * gpx - Ptx * gpz,
                           Ptx * gpy - Pty * gpx };
            accum_point(acc, J, rr, 1.0f, 28);
        }

        // ---- deterministic in-block reduction: wave shuffle -> LDS ----
        #pragma unroll
        for (int q = 0; q < NACC; q++) {
            float vq = acc[q];
            #pragma unroll
            for (int off = 32; off >= 1; off >>= 1) vq += __shfl_xor(vq, off);
            acc[q] = vq;
        }
        int wave = tid >> 6;
        int lane = tid & 63;
        __syncthreads();   // protect lds[][] reuse across iterations
        if (lane == 0) {
            #pragma unroll
            for (int q = 0; q < NACC; q++) lds[wave][q] = acc[q];
        }
        __syncthreads();
        float* pbuf = ws + ((it & 1) ? WS_P1 : WS_P0);
        if (tid < NACC) {
            int q = tid;
            float s = lds[0][q] + lds[1][q] + lds[2][q] + lds[3][q];
            st_f_sc1(&pbuf[q * MB + bid], s);   // at coherent point; L2 untouched
        }
        __syncthreads();   // drains sc1 stores (vmcnt) before tid0 arrives
        if (tid == 0) arrive(bar, bid);
        sync_no++;

        if (bid == 0) {
            // ---- single-solver: reduce all partials + solve (block0 only) ----
            if (tid == 0) {
                while (ld_i_sc1(bar + 16) < NLEAF * sync_no) __builtin_amdgcn_s_sleep(1);
            }
            __syncthreads();           // all partials visible at coherent point
            if (tid < NACC * 8) {
                int q = tid >> 3, s = tid & 7;
                const int CH = MB / 8;            // 50
                int lo = s * CH, hi = lo + CH;
                float* row = pbuf + q * MB;
                double a0 = 0, a1 = 0, a2 = 0, a3 = 0, a4 = 0, a5 = 0, a6 = 0, a7 = 0;
                int i = lo;
                for (; i + 8 <= hi; i += 8) {   // 48 of 50
                    a0 += (double)ld_f_sc1(&row[i]);
                    a1 += (double)ld_f_sc1(&row[i + 1]);
                    a2 += (double)ld_f_sc1(&row[i + 2]);
                    a3 += (double)ld_f_sc1(&row[i + 3]);
                    a4 += (double)ld_f_sc1(&row[i + 4]);
                    a5 += (double)ld_f_sc1(&row[i + 5]);
                    a6 += (double)ld_f_sc1(&row[i + 6]);
                    a7 += (double)ld_f_sc1(&row[i + 7]);
                }
                for (; i < hi; i++) a0 += (double)ld_f_sc1(&row[i]);   // remainder 2
                part8[tid] = (((a0 + a1) + (a2 + a3)) + ((a4 + a5) + (a6 + a7)));
            }
            __syncthreads();
            if (tid < NACC) {
                double sm = 0.0;
                #pragma unroll
                for (int s = 0; s < 8; s++) sm += part8[tid * 8 + s];
                sums[tid] = sm;
            }
            __syncthreads();
            if (tid == 0) {
                double M[6][7];
                int k = 0;
                for (int i = 0; i < 6; i++)
                    for (int j = i; j < 6; j++) { M[i][j] = sums[k]; M[j][i] = sums[k]; k++; }
                for (int i = 0; i < 6; i++) { M[i][6] = sums[21 + i]; M[i][i] += 1e-9; }
                double new_cost = 10.0 * sums[27] / (double)NPIX + sums[28] / (double)NPIX;

                for (int c = 0; c < 6; c++) {
                    int piv = c; double mx = fabs(M[c][c]);
                    for (int r2 = c + 1; r2 < 6; r2++) {
                        double a = fabs(M[r2][c]);
                        if (a > mx) { mx = a; piv = r2; }
                    }
                    if (piv != c)
                        for (int j2 = 0; j2 < 7; j2++) { double tmp = M[c][j2]; M[c][j2] = M[piv][j2]; M[piv][j2] = tmp; }
                    double inv = 1.0 / M[c][c];
                    for (int r2 = c + 1; r2 < 6; r2++) {
                        double f = M[r2][c] * inv;
                        for (int j2 = c; j2 < 7; j2++) M[r2][j2] -= f * M[c][j2];
                    }
                }
                double x0[6];
                for (int i = 5; i >= 0; i--) {
                    double s = M[i][6];
                    for (int j = i + 1; j < 6; j++) s -= M[i][j] * x0[j];
                    x0[i] = s / M[i][i];
                }

                double nx0 = 0.0, nx = 0.0;
                float xf[6];
                for (int i = 0; i < 6; i++) {
                    xf[i] = sx[i];
                    nx0 += x0[i] * x0[i];
                    nx  += (double)xf[i] * (double)xf[i];
                }
                nx0 = sqrt(nx0); nx = sqrt(nx);
                bool convold = (sconv != 0.f);
                bool c2 = convold || (new_cost < 1e-3) || (nx0 < 1e-8 * (1e-8 + nx));
                float xn[6];
                for (int i = 0; i < 6; i++)
                    xn[i] = c2 ? xf[i] : (float)((double)xf[i] - x0[i]);
                for (int i = 0; i < 6; i++) sx[i] = xn[i];
                sconv = c2 ? 1.f : 0.f;
                if (!convold) scost = (float)new_cost;

                float T[16];
                exp_se3_f32(xn, T);
                // publish pose packet, then epoch (ordered by vmcnt drain)
                st_f_sc1(&pkt[0], T[0]);  st_f_sc1(&pkt[1], T[1]);  st_f_sc1(&pkt[2], T[2]);
                st_f_sc1(&pkt[3], T[4]);  st_f_sc1(&pkt[4], T[5]);  st_f_sc1(&pkt[5], T[6]);
                st_f_sc1(&pkt[6], T[8]);  st_f_sc1(&pkt[7], T[9]);  st_f_sc1(&pkt[8], T[10]);
                st_f_sc1(&pkt[9], T[3]);  st_f_sc1(&pkt[10], T[7]); st_f_sc1(&pkt[11], T[11]);
                if (it == 19) {
                    for (int i = 0; i < 16; i++) out[i] = T[i];
                    out[16] = scost;
                }
                asm volatile("s_waitcnt vmcnt(0)" ::: "memory");
                __hip_atomic_store(bar, sync_no, __ATOMIC_RELAXED, __HIP_MEMORY_SCOPE_AGENT);
            }
        }

        // ---- all blocks: wait for pose epoch, mirror packet into LDS ----
        if (tid == 0) {
            while (ld_i_sc1(bar) < sync_no) __builtin_amdgcn_s_sleep(4);
            asm volatile("" ::: "memory");
            #pragma unroll
            for (int i = 0; i < 12; i++) spose[i] = ld_f_sc1(&pkt[i]);
        }
        __syncthreads();
    }
}

extern "C" void kernel_launch(void* const* d_in, const int* in_sizes, int n_in,
                              void* d_out, int out_size, void* d_ws, size_t ws_size,
                              hipStream_t stream) {
    const float* depth_ref      = (const float*)d_in[0];
    const float* normals_ref    = (const float*)d_in[1];
    const float* gray_ref       = (const float*)d_in[2];
    const float* gray_target    = (const float*)d_in[3];
    const float* points_target  = (const float*)d_in[4];
    const float* normals_target = (const float*)d_in[5];
    const float* K              = (const float*)d_in[6];
    float* ws  = (float*)d_ws;
    float* out = (float*)d_out;

    // zero epoch/root/leaf counters (captured into the graph; replays deterministically)
    hipMemsetAsync(d_ws, 0, 2048, stream);

    bool big = ws_size >= (size_t)WS_BIG_END * sizeof(float);
    if (big) {
        hipLaunchKernelGGL((fused_icp<1>), dim3(MB), dim3(TPB), 0, stream,
                           depth_ref, normals_ref, gray_ref, gray_target,
                           points_target, normals_target, K, ws, out);
    } else {
        hipLaunchKernelGGL((fused_icp<0>), dim3(MB), dim3(TPB), 0, stream,
                           depth_ref, normals_ref, gray_ref, gray_target,
                           points_target, normals_target, K, ws, out);
    }
}

// Round 8
// 490.185 us; speedup vs baseline: 3.5004x; 1.0981x over previous
//
#include <hip/hip_runtime.h>
#include <math.h>

#define HH 480
#define WW 640
#define NPIX (HH*WW)
#define NACC 29           // 21 (A upper tri) + 6 (b) + 1 (sum r_icp^2) + 1 (sum r_rgb^2)
#define TPB 256
#define NBLK 1024         // all co-resident: __launch_bounds__(256,4) -> 4 blk/CU * 256 CU
#define PPB 300           // pixels per block: 1024*300 = 307200 = NPIX exact
#define NLEAF 16
#define LSZ (NBLK/NLEAF)  // 64 blocks per leaf
#define PB NBLK           // partials row stride

// d_ws layout (first 4096 BYTES zeroed by hipMemsetAsync each launch):
//   int[16]            root arrive counter
//   int[128+16*i]      leaf arrive counter i (i<16, 64B-separated lines)
//   int[512+16*i]      leaf epoch slot i    (i<16, 64B-separated lines)
//   float[400..412)    pose packet R(9),t(3)            (sc1-only)
//   double[ws+1024]    lp[q*16+leaf] level-2 partials   (sc1-only, 29x16)
//   float[2048 ..)     pbuf[q*PB+wid] level-1 partials  (sc1-only, 29x1024)
//   PACKED only:
//   [WS_G4 ..)  float4/px (grayT, gx, gy, 0)
//   [WS_NR ..)  float4/px (nr0, nr1, nr2, depth_ref)
//   [WS_PZ ..)  float4/px (qz, nq0, nq1, nq2)
#define WS_PKT 400
#define WS_LP 1024
#define WS_P0 2048
#define WS_G4 32768
#define WS_NR (WS_G4 + NPIX*4)
#define WS_PZ (WS_NR + NPIX*4)
#define WS_BIG_END (WS_PZ + NPIX*4)   // 3719168 floats ~= 14.88 MB

__device__ __forceinline__ int ld_i_sc1(const int* p) {
    return __hip_atomic_load(p, __ATOMIC_RELAXED, __HIP_MEMORY_SCOPE_AGENT);
}
__device__ __forceinline__ float ld_f_sc1(const float* p) {
    return __hip_atomic_load(p, __ATOMIC_RELAXED, __HIP_MEMORY_SCOPE_AGENT);
}
__device__ __forceinline__ void st_f_sc1(float* p, float v) {
    __hip_atomic_store(p, v, __ATOMIC_RELAXED, __HIP_MEMORY_SCOPE_AGENT);
}
__device__ __forceinline__ double ld_d_sc1(const double* p) {
    return __hip_atomic_load(p, __ATOMIC_RELAXED, __HIP_MEMORY_SCOPE_AGENT);
}
__device__ __forceinline__ void st_d_sc1(double* p, double v) {
    __hip_atomic_store(p, v, __ATOMIC_RELAXED, __HIP_MEMORY_SCOPE_AGENT);
}

__device__ __forceinline__ float gradu(const float* g, int v, int u) {
    const float* row = g + v * WW;
    if (u == 0)      return row[1] - row[0];
    if (u == WW - 1) return row[WW - 1] - row[WW - 2];
    return 0.5f * (row[u + 1] - row[u - 1]);
}
__device__ __forceinline__ float gradv(const float* g, int v, int u) {
    if (v == 0)      return g[WW + u] - g[u];
    if (v == HH - 1) return g[(HH - 1) * WW + u] - g[(HH - 2) * WW + u];
    return 0.5f * (g[(v + 1) * WW + u] - g[(v - 1) * WW + u]);
}

__device__ void exp_se3_f32(const float* xi, float* T) {
    float v0 = xi[0], v1 = xi[1], v2 = xi[2];
    float w0 = xi[3], w1 = xi[4], w2 = xi[5];
    float th2 = w0 * w0 + w1 * w1 + w2 * w2;
    float th = sqrtf(th2);
    bool small = th < 1e-8f;
    float ths = small ? 1.0f : th;
    float A = small ? (1.0f - th2 / 6.0f) : (sinf(ths) / ths);
    float B = small ? (0.5f - th2 / 24.0f) : ((1.0f - cosf(ths)) / (ths * ths));
    float C = small ? (1.0f / 6.0f - th2 / 120.0f) : ((ths - sinf(ths)) / (ths * ths * ths));
    float Wx[9] = { 0.f, -w2,  w1,
                    w2,  0.f, -w0,
                   -w1,  w0,  0.f };
    float W2[9];
    #pragma unroll
    for (int i = 0; i < 3; i++)
        #pragma unroll
        for (int j = 0; j < 3; j++) {
            float s = 0.f;
            #pragma unroll
            for (int k = 0; k < 3; k++) s += Wx[i * 3 + k] * Wx[k * 3 + j];
            W2[i * 3 + j] = s;
        }
    float R[9], V[9];
    #pragma unroll
    for (int i = 0; i < 9; i++) {
        float id = (i == 0 || i == 4 || i == 8) ? 1.0f : 0.0f;
        R[i] = id + A * Wx[i] + B * W2[i];
        V[i] = id + B * Wx[i] + C * W2[i];
    }
    float t0 = V[0] * v0 + V[1] * v1 + V[2] * v2;
    float t1 = V[3] * v0 + V[4] * v1 + V[5] * v2;
    float t2 = V[6] * v0 + V[7] * v1 + V[8] * v2;
    T[0] = R[0]; T[1] = R[1]; T[2]  = R[2]; T[3]  = t0;
    T[4] = R[3]; T[5] = R[4]; T[6]  = R[5]; T[7]  = t1;
    T[8] = R[6]; T[9] = R[7]; T[10] = R[8]; T[11] = t2;
    T[12] = 0.f; T[13] = 0.f; T[14] = 0.f; T[15] = 1.f;
}

__device__ __forceinline__ void accum_point(float* acc, const float* J, float r, float w, int costslot) {
    int k = 0;
    #pragma unroll
    for (int i = 0; i < 6; i++) {
        #pragma unroll
        for (int j = i; j < 6; j++) { acc[k] += w * (J[i] * J[j]); k++; }
        acc[21 + i] += w * (J[i] * r);
    }
    acc[costslot] += r * r;
}

template <int PACKED>
__global__ __launch_bounds__(TPB, 4) void fused_icp(
    const float* __restrict__ depth_ref,
    const float* __restrict__ normals_ref,
    const float* __restrict__ gray_ref,
    const float* __restrict__ gray_target,
    const float* __restrict__ points_target,
    const float* __restrict__ normals_target,
    const float* __restrict__ K,
    float* __restrict__ ws,
    float* __restrict__ out)
{
    const int tid = threadIdx.x;
    // XCD-banding swizzle: XCD x (= bid%8 round-robin) gets contiguous wids
    // [x*128, x*128+128) => contiguous 60-row image band => gathers stay in
    // that XCD's own L2. Pure perf remap; work/partials indexed by wid.
    const int wid = (blockIdx.x & 7) * (NBLK / 8) + (blockIdx.x >> 3);
    const int leaf = wid / LSZ;
    const float fx = K[0], cx = K[2], fy = K[4], cy = K[5];
    int* bar = (int*)ws;
    float* pkt = ws + WS_PKT;
    double* lp = (double*)(ws + WS_LP);
    float* pbuf = ws + WS_P0;
    int sync_no = 0;
    float4* g4  = (float4*)(ws + WS_G4);
    float4* nr4 = (float4*)(ws + WS_NR);
    float4* pz4 = (float4*)(ws + WS_PZ);

    __shared__ float spose[12];
    __shared__ float sx[6];
    __shared__ float sconv, scost;
    __shared__ float lds[4][NACC];
    __shared__ double part8[NACC * 8];
    __shared__ double sums[NACC];
    __shared__ int scloser;

    if (tid == 0) {
        spose[0] = 1.f; spose[1] = 0.f; spose[2] = 0.f;
        spose[3] = 0.f; spose[4] = 1.f; spose[5] = 0.f;
        spose[6] = 0.f; spose[7] = 0.f; spose[8] = 1.f;
        spose[9] = 0.f; spose[10] = 0.f; spose[11] = 0.f;
        #pragma unroll
        for (int i = 0; i < 6; i++) sx[i] = 0.f;
        sconv = 0.f; scost = 0.f;
    }

    // ---- one-time packed-texture precompute (PACKED only) ----
    if (PACKED) {
        int base = wid * PPB;
        for (int k = 0; k < 2; k++) {
            int off = k * TPB + tid;
            if (off >= PPB) break;
            int p = base + off;
            int v = p / WW, u = p - v * WW;
            float4 c;
            c.x = gray_target[p];
            c.y = gradu(gray_target, v, u);
            c.z = gradv(gray_target, v, u);
            c.w = 0.f;
            g4[p] = c;
            float4 n;
            n.x = normals_ref[3 * p];
            n.y = normals_ref[3 * p + 1];
            n.z = normals_ref[3 * p + 2];
            n.w = depth_ref[p];
            nr4[p] = n;
            float4 z;
            z.x = points_target[3 * p + 2];
            z.y = normals_target[3 * p];
            z.z = normals_target[3 * p + 1];
            z.w = normals_target[3 * p + 2];
            pz4[p] = z;
        }
        __threadfence();   // one-time writeback of plain texture stores to coherent point
        sync_no++;         // = 1
        __syncthreads();
        if (tid == 0) {
            int a = __hip_atomic_fetch_add(bar + 128 + 16 * leaf, 1, __ATOMIC_RELAXED, __HIP_MEMORY_SCOPE_AGENT);
            scloser = ((a + 1) == LSZ * sync_no) ? 1 : 0;
        }
        __syncthreads();
        if (scloser && tid == 0)
            __hip_atomic_fetch_add(bar + 16, 1, __ATOMIC_RELAXED, __HIP_MEMORY_SCOPE_AGENT);
        if (wid == 0 && tid == 0) {
            while (ld_i_sc1(bar + 16) < NLEAF * sync_no) __builtin_amdgcn_s_sleep(1);
            asm volatile("s_waitcnt vmcnt(0)" ::: "memory");
            for (int i = 0; i < NLEAF; i++)
                __hip_atomic_store(bar + 512 + 16 * i, sync_no, __ATOMIC_RELAXED, __HIP_MEMORY_SCOPE_AGENT);
        }
        if (tid == 0) {
            while (ld_i_sc1(bar + 512 + 16 * leaf) < sync_no) __builtin_amdgcn_s_sleep(2);
        }
        __syncthreads();
    } else {
        __syncthreads();
    }

    for (int it = 0; it < 20; ++it) {
        const float R00 = spose[0], R01 = spose[1], R02 = spose[2];
        const float R10 = spose[3], R11 = spose[4], R12 = spose[5];
        const float R20 = spose[6], R21 = spose[7], R22 = spose[8];
        const float t0 = spose[9], t1 = spose[10], t2 = spose[11];

        float acc[NACC];
        #pragma unroll
        for (int i = 0; i < NACC; i++) acc[i] = 0.f;

        int base = wid * PPB;
        #pragma unroll
        for (int kk = 0; kk < 2; kk++) {
            int off = kk * TPB + tid;
            if (off >= PPB) break;          // second pass: only tid < 44
            int p = base + off;
            int vv = p / WW;
            int uu = p - vv * WW;

            float nr0, nr1, nr2, Z;
            if (PACKED) {
                float4 n = nr4[p];
                nr0 = n.x; nr1 = n.y; nr2 = n.z; Z = n.w;
            } else {
                Z = depth_ref[p];
                nr0 = normals_ref[3 * p]; nr1 = normals_ref[3 * p + 1]; nr2 = normals_ref[3 * p + 2];
            }
            float Px = ((float)uu - cx) / fx * Z;
            float Py = ((float)vv - cy) / fy * Z;
            float Pz = Z;
            float Ptx = R00 * Px + R01 * Py + R02 * Pz + t0;
            float Pty = R10 * Px + R11 * Py + R12 * Pz + t1;
            float Ptz = R20 * Px + R21 * Py + R22 * Pz + t2;
            bool okz = Ptz > 1e-6f;
            float Zs = okz ? Ptz : 1.0f;
            float u = fx * Ptx / Zs + cx;
            float v = fy * Pty / Zs + cy;
            bool inb = okz && (u >= 0.f) && (u <= (float)(WW - 1)) && (v >= 0.f) && (v <= (float)(HH - 1));
            if (!inb) continue;

            // ---- ICP term ----
            int ui = (int)rintf(u); ui = ui < 0 ? 0 : (ui > WW - 1 ? WW - 1 : ui);
            int vi = (int)rintf(v); vi = vi < 0 ? 0 : (vi > HH - 1 ? HH - 1 : vi);
            int ti = vi * WW + ui;
            float qx, qy, qz, nqx, nqy, nqz;
            if (PACKED) {
                float4 z = pz4[ti];
                qz = z.x; nqx = z.y; nqy = z.z; nqz = z.w;
                qx = (((float)ui) - cx) / fx * qz;   // bitwise == setup's chain
                qy = (((float)vi) - cy) / fy * qz;
            } else {
                qx = points_target[3 * ti]; qy = points_target[3 * ti + 1]; qz = points_target[3 * ti + 2];
                nqx = normals_target[3 * ti]; nqy = normals_target[3 * ti + 1]; nqz = normals_target[3 * ti + 2];
            }
            float dx = Ptx - qx, dy = Pty - qy, dz = Ptz - qz;
            float nrx = R00 * nr0 + R01 * nr1 + R02 * nr2;
            float nry = R10 * nr0 + R11 * nr1 + R12 * nr2;
            float nrz = R20 * nr0 + R21 * nr1 + R22 * nr2;
            const float DIST2 = (float)((200.0 / 15.0) * (200.0 / 15.0));
            if ((dx * dx + dy * dy + dz * dz) < DIST2 &&
                (nrx * nqx + nry * nqy + nrz * nqz) > 0.94f) {
                float r = nqx * dx + nqy * dy + nqz * dz;
                float J[6] = { nqx, nqy, nqz,
                               Pty * nqz - Ptz * nqy,
                               Ptz * nqx - Ptx * nqz,
                               Ptx * nqy - Pty * nqx };
                accum_point(acc, J, r, 10.0f, 27);
            }
            // ---- RGB (photometric) term ----
            float u0f = floorf(u), v0f = floorf(v);
            float du = u - u0f, dv = v - v0f;
            int u0 = (int)u0f; u0 = u0 < 0 ? 0 : (u0 > WW - 1 ? WW - 1 : u0);
            int u1 = (u0 + 1 > WW - 1) ? WW - 1 : u0 + 1;
            int v0 = (int)v0f; v0 = v0 < 0 ? 0 : (v0 > HH - 1 ? HH - 1 : v0);
            int v1 = (v0 + 1 > HH - 1) ? HH - 1 : v0 + 1;
            int i00 = v0 * WW + u0, i01 = v0 * WW + u1, i10 = v1 * WW + u0, i11 = v1 * WW + u1;
            float I00, I01, I10, I11, gx00, gx01, gx10, gx11, gy00, gy01, gy10, gy11;
            if (PACKED) {
                float4 c00 = g4[i00], c01 = g4[i01], c10 = g4[i10], c11 = g4[i11];
                I00 = c00.x; gx00 = c00.y; gy00 = c00.z;
                I01 = c01.x; gx01 = c01.y; gy01 = c01.z;
                I10 = c10.x; gx10 = c10.y; gy10 = c10.z;
                I11 = c11.x; gx11 = c11.y; gy11 = c11.z;
            } else {
                const float* g = gray_target;
                I00 = g[i00]; I01 = g[i01]; I10 = g[i10]; I11 = g[i11];
                gx00 = gradu(g, v0, u0); gx01 = gradu(g, v0, u1);
                gx10 = gradu(g, v1, u0); gx11 = gradu(g, v1, u1);
                gy00 = gradv(g, v0, u0); gy01 = gradv(g, v0, u1);
                gy10 = gradv(g, v1, u0); gy11 = gradv(g, v1, u1);
            }
            float It  = (I00 * (1.f - du) + I01 * du) * (1.f - dv) + (I10 * (1.f - du) + I11 * du) * dv;
            float gxs = (gx00 * (1.f - du) + gx01 * du) * (1.f - dv) + (gx10 * (1.f - du) + gx11 * du) * dv;
            float gys = (gy00 * (1.f - du) + gy01 * du) * (1.f - dv) + (gy10 * (1.f - du) + gy11 * du) * dv;
            float rr = It - gray_ref[p];
            float gpx = gxs * fx / Zs;
            float gpy = gys * fy / Zs;
            float gpz = -(gxs * fx * Ptx + gys * fy * Pty) / (Zs * Zs);
            float J[6] = { gpx, gpy, gpz,
                           Pty * gpz - Ptz * gpy,
                           Ptz * gpx - Ptx * gpz,
                           Ptx * gpy - Pty * gpx };
            accum_point(acc, J, rr, 1.0f, 28);
        }

        // ---- deterministic in-block reduction: wave shuffle -> LDS ----
        #pragma unroll
        for (int q = 0; q < NACC; q++) {
            float vq = acc[q];
            #pragma unroll
            for (int off = 32; off >= 1; off >>= 1) vq += __shfl_xor(vq, off);
            acc[q] = vq;
        }
        int wave = tid >> 6;
        int lane = tid & 63;
        __syncthreads();
        if (lane == 0) {
            #pragma unroll
            for (int q = 0; q < NACC; q++) lds[wave][q] = acc[q];
        }
        __syncthreads();
        if (tid < NACC) {
            int q = tid;
            float s = lds[0][q] + lds[1][q] + lds[2][q] + lds[3][q];
            st_f_sc1(&pbuf[q * PB + wid], s);
        }
        sync_no++;
        __syncthreads();   // drains the sc1 partial stores (vmcnt) before arrive
        if (tid == 0) {
            int a = __hip_atomic_fetch_add(bar + 128 + 16 * leaf, 1, __ATOMIC_RELAXED, __HIP_MEMORY_SCOPE_AGENT);
            scloser = ((a + 1) == LSZ * sync_no) ? 1 : 0;
        }
        __syncthreads();
        if (scloser) {
            // ---- leaf closer: reduce this leaf's 64 partials -> lp[q][leaf] (f64) ----
            if (tid < NACC * 8) {
                int q = tid >> 3, s = tid & 7;
                const float* row = pbuf + q * PB + leaf * LSZ + s * 8;
                double a0 = 0.0;
                #pragma unroll
                for (int j = 0; j < 8; j++) a0 += (double)ld_f_sc1(&row[j]);
                part8[tid] = a0;
            }
            __syncthreads();
            if (tid < NACC) {
                double sm = 0.0;
                #pragma unroll
                for (int s = 0; s < 8; s++) sm += part8[tid * 8 + s];
                st_d_sc1(&lp[tid * NLEAF + leaf], sm);
            }
            __syncthreads();   // drain lp stores before root add
            if (tid == 0)
                __hip_atomic_fetch_add(bar + 16, 1, __ATOMIC_RELAXED, __HIP_MEMORY_SCOPE_AGENT);
        }

        if (wid == 0) {
            // ---- single solver: combine 16 leaf sums + solve ----
            if (tid == 0) {
                while (ld_i_sc1(bar + 16) < NLEAF * sync_no) __builtin_amdgcn_s_sleep(1);
            }
            __syncthreads();
            if (tid < NACC * 8) {
                int q = tid >> 3, s = tid & 7;
                part8[tid] = ld_d_sc1(&lp[q * NLEAF + 2 * s]) + ld_d_sc1(&lp[q * NLEAF + 2 * s + 1]);
            }
            __syncthreads();
            if (tid < NACC) {
                double sm = 0.0;
                #pragma unroll
                for (int s = 0; s < 8; s++) sm += part8[tid * 8 + s];
                sums[tid] = sm;
            }
            __syncthreads();
            if (tid == 0) {
                double M[6][7];
                int k = 0;
                for (int i = 0; i < 6; i++)
                    for (int j = i; j < 6; j++) { M[i][j] = sums[k]; M[j][i] = sums[k]; k++; }
                for (int i = 0; i < 6; i++) { M[i][6] = sums[21 + i]; M[i][i] += 1e-9; }
                double new_cost = 10.0 * sums[27] / (double)NPIX + sums[28] / (double)NPIX;

                for (int c = 0; c < 6; c++) {
                    int piv = c; double mx = fabs(M[c][c]);
                    for (int r2 = c + 1; r2 < 6; r2++) {
                        double a = fabs(M[r2][c]);
                        if (a > mx) { mx = a; piv = r2; }
                    }
                    if (piv != c)
                        for (int j2 = 0; j2 < 7; j2++) { double tmp = M[c][j2]; M[c][j2] = M[piv][j2]; M[piv][j2] = tmp; }
                    double inv = 1.0 / M[c][c];
                    for (int r2 = c + 1; r2 < 6; r2++) {
                        double f = M[r2][c] * inv;
                        for (int j2 = c; j2 < 7; j2++) M[r2][j2] -= f * M[c][j2];
                    }
                }
                double x0[6];
                for (int i = 5; i >= 0; i--) {
                    double s = M[i][6];
                    for (int j = i + 1; j < 6; j++) s -= M[i][j] * x0[j];
                    x0[i] = s / M[i][i];
                }

                double nx0 = 0.0, nx = 0.0;
                float xf[6];
                for (int i = 0; i < 6; i++) {
                    xf[i] = sx[i];
                    nx0 += x0[i] * x0[i];
                    nx  += (double)xf[i] * (double)xf[i];
                }
                nx0 = sqrt(nx0); nx = sqrt(nx);
                bool convold = (sconv != 0.f);
                bool c2 = convold || (new_cost < 1e-3) || (nx0 < 1e-8 * (1e-8 + nx));
                float xn[6];
                for (int i = 0; i < 6; i++)
                    xn[i] = c2 ? xf[i] : (float)((double)xf[i] - x0[i]);
                for (int i = 0; i < 6; i++) sx[i] = xn[i];
                sconv = c2 ? 1.f : 0.f;
                if (!convold) scost = (float)new_cost;

                float T[16];
                exp_se3_f32(xn, T);
                st_f_sc1(&pkt[0], T[0]);  st_f_sc1(&pkt[1], T[1]);  st_f_sc1(&pkt[2], T[2]);
                st_f_sc1(&pkt[3], T[4]);  st_f_sc1(&pkt[4], T[5]);  st_f_sc1(&pkt[5], T[6]);
                st_f_sc1(&pkt[6], T[8]);  st_f_sc1(&pkt[7], T[9]);  st_f_sc1(&pkt[8], T[10]);
                st_f_sc1(&pkt[9], T[3]);  st_f_sc1(&pkt[10], T[7]); st_f_sc1(&pkt[11], T[11]);
                if (it == 19) {
                    for (int i = 0; i < 16; i++) out[i] = T[i];
                    out[16] = scost;
                }
                asm volatile("s_waitcnt vmcnt(0)" ::: "memory");   // pkt visible before epoch
                for (int i = 0; i < NLEAF; i++)
                    __hip_atomic_store(bar + 512 + 16 * i, sync_no, __ATOMIC_RELAXED, __HIP_MEMORY_SCOPE_AGENT);
            }
        }

        // ---- all blocks: wait leaf epoch, mirror pose packet into LDS ----
        if (tid == 0) {
            while (ld_i_sc1(bar + 512 + 16 * leaf) < sync_no) __builtin_amdgcn_s_sleep(2);
            asm volatile("" ::: "memory");
            #pragma unroll
            for (int i = 0; i < 12; i++) spose[i] = ld_f_sc1(&pkt[i]);
        }
        __syncthreads();
    }
}

extern "C" void kernel_launch(void* const* d_in, const int* in_sizes, int n_in,
                              void* d_out, int out_size, void* d_ws, size_t ws_size,
                              hipStream_t stream) {
    const float* depth_ref      = (const float*)d_in[0];
    const float* normals_ref    = (const float*)d_in[1];
    const float* gray_ref       = (const float*)d_in[2];
    const float* gray_target    = (const float*)d_in[3];
    const float* points_target  = (const float*)d_in[4];
    const float* normals_target = (const float*)d_in[5];
    const float* K              = (const float*)d_in[6];
    float* ws  = (float*)d_ws;
    float* out = (float*)d_out;

    // zero counters/epochs (captured into the graph; replays deterministically)
    hipMemsetAsync(d_ws, 0, 4096, stream);

    bool big = ws_size >= (size_t)WS_BIG_END * sizeof(float);
    if (big) {
        hipLaunchKernelGGL((fused_icp<1>), dim3(NBLK), dim3(TPB), 0, stream,
                           depth_ref, normals_ref, gray_ref, gray_target,
                           points_target, normals_target, K, ws, out);
    } else {
        hipLaunchKernelGGL((fused_icp<0>), dim3(NBLK), dim3(TPB), 0, stream,
                           depth_ref, normals_ref, gray_ref, gray_target,
                           points_target, normals_target, K, ws, out);
    }
}

// Round 10
// 444.510 us; speedup vs baseline: 3.8601x; 1.1028x over previous
//
#include <hip/hip_runtime.h>
#include <math.h>

#define HH 480
#define WW 640
#define NPIX (HH*WW)
#define NACC 29            // 21 (A upper tri) + 6 (b) + 1 r_icp^2 + 1 r_rgb^2
#define TPB_B 512
#define NB_B 600           // 600*512 = 307200 = NPIX exact, 1 px/thread
#define TPB_C 256
#define PB 600             // partials row stride
#define CH 75              // 600/8 consecutive floats per stage-1 thread

// d_ws float-index layout (all plain cached loads/stores; kernel boundaries
// provide ordering — no atomics, no fences, no spin loops anywhere):
//   [0..11]   pose: R row-major(9), t(3)   (written by init/solve, read by map)
//   [12]      conv flag   [13] cost   [16..21] x(6)
//   [WS_P..)  partials transposed [q][block], 29*600 floats
//   PACKED only:
//   [WS_G4..) float4/px (grayT, gx, gy, 0)
//   [WS_NR..) float4/px (nr0, nr1, nr2, depth_ref)
//   [WS_PZ..) float4/px (qz, nq0, nq1, nq2)
#define WS_P 512
#define WS_G4 18432                       // byte 73728, 16B-aligned
#define WS_NR (WS_G4 + NPIX*4)
#define WS_PZ (WS_NR + NPIX*4)
#define WS_BIG_END (WS_PZ + NPIX*4)       // 3704832 floats ~ 14.82 MB

__device__ __forceinline__ float gradu(const float* g, int v, int u) {
    const float* row = g + v * WW;
    if (u == 0)      return row[1] - row[0];
    if (u == WW - 1) return row[WW - 1] - row[WW - 2];
    return 0.5f * (row[u + 1] - row[u - 1]);
}
__device__ __forceinline__ float gradv(const float* g, int v, int u) {
    if (v == 0)      return g[WW + u] - g[u];
    if (v == HH - 1) return g[(HH - 1) * WW + u] - g[(HH - 2) * WW + u];
    return 0.5f * (g[(v + 1) * WW + u] - g[(v - 1) * WW + u]);
}

__device__ void exp_se3_f32(const float* xi, float* T) {
    float v0 = xi[0], v1 = xi[1], v2 = xi[2];
    float w0 = xi[3], w1 = xi[4], w2 = xi[5];
    float th2 = w0 * w0 + w1 * w1 + w2 * w2;
    float th = sqrtf(th2);
    bool small = th < 1e-8f;
    float ths = small ? 1.0f : th;
    float A = small ? (1.0f - th2 / 6.0f) : (sinf(ths) / ths);
    float B = small ? (0.5f - th2 / 24.0f) : ((1.0f - cosf(ths)) / (ths * ths));
    float C = small ? (1.0f / 6.0f - th2 / 120.0f) : ((ths - sinf(ths)) / (ths * ths * ths));
    float Wx[9] = { 0.f, -w2,  w1,
                    w2,  0.f, -w0,
                   -w1,  w0,  0.f };
    float W2[9];
    #pragma unroll
    for (int i = 0; i < 3; i++)
        #pragma unroll
        for (int j = 0; j < 3; j++) {
            float s = 0.f;
            #pragma unroll
            for (int k = 0; k < 3; k++) s += Wx[i * 3 + k] * Wx[k * 3 + j];
            W2[i * 3 + j] = s;
        }
    float R[9], V[9];
    #pragma unroll
    for (int i = 0; i < 9; i++) {
        float id = (i == 0 || i == 4 || i == 8) ? 1.0f : 0.0f;
        R[i] = id + A * Wx[i] + B * W2[i];
        V[i] = id + B * Wx[i] + C * W2[i];
    }
    float t0 = V[0] * v0 + V[1] * v1 + V[2] * v2;
    float t1 = V[3] * v0 + V[4] * v1 + V[5] * v2;
    float t2 = V[6] * v0 + V[7] * v1 + V[8] * v2;
    T[0] = R[0]; T[1] = R[1]; T[2]  = R[2]; T[3]  = t0;
    T[4] = R[3]; T[5] = R[4]; T[6]  = R[5]; T[7]  = t1;
    T[8] = R[6]; T[9] = R[7]; T[10] = R[8]; T[11] = t2;
    T[12] = 0.f; T[13] = 0.f; T[14] = 0.f; T[15] = 1.f;
}

__device__ __forceinline__ void accum_point(float* acc, const float* J, float r, float w, int costslot) {
    int k = 0;
    #pragma unroll
    for (int i = 0; i < 6; i++) {
        #pragma unroll
        for (int j = i; j < 6; j++) { acc[k] += w * (J[i] * J[j]); k++; }
        acc[21 + i] += w * (J[i] * r);
    }
    acc[costslot] += r * r;
}

// ---- Kernel A: one-time state init + packed-texture build (plain stores) ----
template <int PACKED>
__global__ __launch_bounds__(TPB_B) void pack_init(
    const float* __restrict__ depth_ref,
    const float* __restrict__ normals_ref,
    const float* __restrict__ gray_target,
    const float* __restrict__ points_target,
    const float* __restrict__ normals_target,
    float* __restrict__ ws)
{
    if (blockIdx.x == 0 && threadIdx.x == 0) {
        ws[0] = 1.f; ws[1] = 0.f; ws[2] = 0.f;
        ws[3] = 0.f; ws[4] = 1.f; ws[5] = 0.f;
        ws[6] = 0.f; ws[7] = 0.f; ws[8] = 1.f;
        ws[9] = 0.f; ws[10] = 0.f; ws[11] = 0.f;
        ws[12] = 0.f; ws[13] = 0.f;
        #pragma unroll
        for (int i = 0; i < 6; i++) ws[16 + i] = 0.f;
    }
    if (PACKED) {
        int p = blockIdx.x * TPB_B + threadIdx.x;
        int v = p / WW, u = p - v * WW;
        float4* g4  = (float4*)(ws + WS_G4);
        float4* nr4 = (float4*)(ws + WS_NR);
        float4* pz4 = (float4*)(ws + WS_PZ);
        float4 c;
        c.x = gray_target[p];
        c.y = gradu(gray_target, v, u);
        c.z = gradv(gray_target, v, u);
        c.w = 0.f;
        g4[p] = c;
        float4 n;
        n.x = normals_ref[3 * p];
        n.y = normals_ref[3 * p + 1];
        n.z = normals_ref[3 * p + 2];
        n.w = depth_ref[p];
        nr4[p] = n;
        float4 z;
        z.x = points_target[3 * p + 2];
        z.y = normals_target[3 * p];
        z.z = normals_target[3 * p + 1];
        z.w = normals_target[3 * p + 2];
        pz4[p] = z;
    }
}

// ---- Kernel B: map + block-reduce -> 29x600 transposed partials ----
template <int PACKED>
__global__ __launch_bounds__(TPB_B) void map_reduce(
    const float* __restrict__ depth_ref,
    const float* __restrict__ normals_ref,
    const float* __restrict__ gray_ref,
    const float* __restrict__ gray_target,
    const float* __restrict__ points_target,
    const float* __restrict__ normals_target,
    const float* __restrict__ K,
    float* __restrict__ ws)
{
    const int tid = threadIdx.x;
    const int bid = blockIdx.x;
    const float fx = K[0], cx = K[2], fy = K[4], cy = K[5];
    const float4* g4  = (const float4*)(ws + WS_G4);
    const float4* nr4 = (const float4*)(ws + WS_NR);
    const float4* pz4 = (const float4*)(ws + WS_PZ);

    __shared__ float spose[12];
    __shared__ float lds[8][NACC];
    if (tid < 12) spose[tid] = ws[tid];
    __syncthreads();
    const float R00 = spose[0], R01 = spose[1], R02 = spose[2];
    const float R10 = spose[3], R11 = spose[4], R12 = spose[5];
    const float R20 = spose[6], R21 = spose[7], R22 = spose[8];
    const float t0 = spose[9], t1 = spose[10], t2 = spose[11];

    float acc[NACC];
    #pragma unroll
    for (int i = 0; i < NACC; i++) acc[i] = 0.f;

    {
        int p = bid * TPB_B + tid;        // exactly 1 px/thread
        int vv = p / WW;
        int uu = p - vv * WW;

        float nr0, nr1, nr2, Z;
        if (PACKED) {
            float4 n = nr4[p];
            nr0 = n.x; nr1 = n.y; nr2 = n.z; Z = n.w;
        } else {
            Z = depth_ref[p];
            nr0 = normals_ref[3 * p]; nr1 = normals_ref[3 * p + 1]; nr2 = normals_ref[3 * p + 2];
        }
        float Px = ((float)uu - cx) / fx * Z;
        float Py = ((float)vv - cy) / fy * Z;
        float Pz = Z;
        float Ptx = R00 * Px + R01 * Py + R02 * Pz + t0;
        float Pty = R10 * Px + R11 * Py + R12 * Pz + t1;
        float Ptz = R20 * Px + R21 * Py + R22 * Pz + t2;
        bool okz = Ptz > 1e-6f;
        float Zs = okz ? Ptz : 1.0f;
        float u = fx * Ptx / Zs + cx;
        float v = fy * Pty / Zs + cy;
        bool inb = okz && (u >= 0.f) && (u <= (float)(WW - 1)) && (v >= 0.f) && (v <= (float)(HH - 1));
        if (inb) {
            // ---- ICP term ----
            int ui = (int)rintf(u); ui = ui < 0 ? 0 : (ui > WW - 1 ? WW - 1 : ui);
            int vi = (int)rintf(v); vi = vi < 0 ? 0 : (vi > HH - 1 ? HH - 1 : vi);
            int ti = vi * WW + ui;
            float qx, qy, qz, nqx, nqy, nqz;
            if (PACKED) {
                float4 z = pz4[ti];
                qz = z.x; nqx = z.y; nqy = z.z; nqz = z.w;
                qx = (((float)ui) - cx) / fx * qz;   // bitwise == setup's chain
                qy = (((float)vi) - cy) / fy * qz;
            } else {
                qx = points_target[3 * ti]; qy = points_target[3 * ti + 1]; qz = points_target[3 * ti + 2];
                nqx = normals_target[3 * ti]; nqy = normals_target[3 * ti + 1]; nqz = normals_target[3 * ti + 2];
            }
            float dx = Ptx - qx, dy = Pty - qy, dz = Ptz - qz;
            float nrx = R00 * nr0 + R01 * nr1 + R02 * nr2;
            float nry = R10 * nr0 + R11 * nr1 + R12 * nr2;
            float nrz = R20 * nr0 + R21 * nr1 + R22 * nr2;
            const float DIST2 = (float)((200.0 / 15.0) * (200.0 / 15.0));
            if ((dx * dx + dy * dy + dz * dz) < DIST2 &&
                (nrx * nqx + nry * nqy + nrz * nqz) > 0.94f) {
                float r = nqx * dx + nqy * dy + nqz * dz;
                float J[6] = { nqx, nqy, nqz,
                               Pty * nqz - Ptz * nqy,
                               Ptz * nqx - Ptx * nqz,
                               Ptx * nqy - Pty * nqx };
                accum_point(acc, J, r, 10.0f, 27);
            }
            // ---- RGB (photometric) term ----
            float u0f = floorf(u), v0f = floorf(v);
            float du = u - u0f, dv = v - v0f;
            int u0 = (int)u0f; u0 = u0 < 0 ? 0 : (u0 > WW - 1 ? WW - 1 : u0);
            int u1 = (u0 + 1 > WW - 1) ? WW - 1 : u0 + 1;
            int v0 = (int)v0f; v0 = v0 < 0 ? 0 : (v0 > HH - 1 ? HH - 1 : v0);
            int v1 = (v0 + 1 > HH - 1) ? HH - 1 : v0 + 1;
            int i00 = v0 * WW + u0, i01 = v0 * WW + u1, i10 = v1 * WW + u0, i11 = v1 * WW + u1;
            float I00, I01, I10, I11, gx00, gx01, gx10, gx11, gy00, gy01, gy10, gy11;
            if (PACKED) {
                float4 c00 = g4[i00], c01 = g4[i01], c10 = g4[i10], c11 = g4[i11];
                I00 = c00.x; gx00 = c00.y; gy00 = c00.z;
                I01 = c01.x; gx01 = c01.y; gy01 = c01.z;
                I10 = c10.x; gx10 = c10.y; gy10 = c10.z;
                I11 = c11.x; gx11 = c11.y; gy11 = c11.z;
            } else {
                const float* g = gray_target;
                I00 = g[i00]; I01 = g[i01]; I10 = g[i10]; I11 = g[i11];
                gx00 = gradu(g, v0, u0); gx01 = gradu(g, v0, u1);
                gx10 = gradu(g, v1, u0); gx11 = gradu(g, v1, u1);
                gy00 = gradv(g, v0, u0); gy01 = gradv(g, v0, u1);
                gy10 = gradv(g, v1, u0); gy11 = gradv(g, v1, u1);
            }
            float It  = (I00 * (1.f - du) + I01 * du) * (1.f - dv) + (I10 * (1.f - du) + I11 * du) * dv;
            float gxs = (gx00 * (1.f - du) + gx01 * du) * (1.f - dv) + (gx10 * (1.f - du) + gx11 * du) * dv;
            float gys = (gy00 * (1.f - du) + gy01 * du) * (1.f - dv) + (gy10 * (1.f - du) + gy11 * du) * dv;
            float rr = It - gray_ref[p];
            float gpx = gxs * fx / Zs;
            float gpy = gys * fy / Zs;
            float gpz = -(gxs * fx * Ptx + gys * fy * Pty) / (Zs * Zs);
            float J[6] = { gpx, gpy, gpz,
                           Pty * gpz - Ptz * gpy,
                           Ptz * gpx - Ptx * gpz,
                           Ptx * gpy - Pty * gpx };
            accum_point(acc, J, rr, 1.0f, 28);
        }
    }

    // ---- deterministic in-block reduction: wave shuffle -> LDS -> partial ----
    #pragma unroll
    for (int q = 0; q < NACC; q++) {
        float vq = acc[q];
        #pragma unroll
        for (int off = 32; off >= 1; off >>= 1) vq += __shfl_xor(vq, off);
        acc[q] = vq;
    }
    int wave = tid >> 6;
    int lane = tid & 63;
    if (lane == 0) {
        #pragma unroll
        for (int q = 0; q < NACC; q++) lds[wave][q] = acc[q];
    }
    __syncthreads();
    if (tid < NACC) {
        int q = tid;
        float s = ((lds[0][q] + lds[1][q]) + (lds[2][q] + lds[3][q]))
                + ((lds[4][q] + lds[5][q]) + (lds[6][q] + lds[7][q]));
        ws[WS_P + q * PB + bid] = s;      // transposed [q][block]
    }
}

// ---- Kernel C: final reduce (f64) + 6x6 solve + pose update ----
__global__ __launch_bounds__(TPB_C) void solve_update(float* __restrict__ ws,
                                                      float* __restrict__ out,
                                                      int final_iter)
{
    __shared__ double part8[NACC * 8];
    __shared__ double sums[NACC];
    int tid = threadIdx.x;
    const float* part = ws + WS_P;
    // Stage 1: 29 q * 8 threads, each reads CH=75 CONSECUTIVE floats with 4
    // independent accumulators (loads pipeline; remainder loop kept!).
    if (tid < NACC * 8) {
        int q = tid >> 3, s = tid & 7;
        const float* row = part + q * PB + s * CH;
        double a0 = 0.0, a1 = 0.0, a2 = 0.0, a3 = 0.0;
        int i = 0;
        for (; i + 4 <= CH; i += 4) {
            a0 += (double)row[i];
            a1 += (double)row[i + 1];
            a2 += (double)row[i + 2];
            a3 += (double)row[i + 3];
        }
        for (; i < CH; i++) a0 += (double)row[i];   // CH=75 -> 3 remainder
        part8[tid] = ((a0 + a1) + (a2 + a3));
    }
    __syncthreads();
    if (tid < NACC) {
        double sm = 0.0;
        #pragma unroll
        for (int s = 0; s < 8; s++) sm += part8[tid * 8 + s];
        sums[tid] = sm;
    }
    __syncthreads();
    if (tid == 0) {
        double M[6][7];
        int k = 0;
        for (int i = 0; i < 6; i++)
            for (int j = i; j < 6; j++) { M[i][j] = sums[k]; M[j][i] = sums[k]; k++; }
        for (int i = 0; i < 6; i++) { M[i][6] = sums[21 + i]; M[i][i] += 1e-9; }
        double new_cost = 10.0 * sums[27] / (double)NPIX + sums[28] / (double)NPIX;

        // 6x6 Gaussian elimination with partial pivoting (f64)
        for (int c = 0; c < 6; c++) {
            int piv = c; double mx = fabs(M[c][c]);
            for (int r2 = c + 1; r2 < 6; r2++) {
                double a = fabs(M[r2][c]);
                if (a > mx) { mx = a; piv = r2; }
            }
            if (piv != c)
                for (int j2 = 0; j2 < 7; j2++) { double tmp = M[c][j2]; M[c][j2] = M[piv][j2]; M[piv][j2] = tmp; }
            double inv = 1.0 / M[c][c];
            for (int r2 = c + 1; r2 < 6; r2++) {
                double f = M[r2][c] * inv;
                for (int j2 = c; j2 < 7; j2++) M[r2][j2] -= f * M[c][j2];
            }
        }
        double x0[6];
        for (int i = 5; i >= 0; i--) {
            double s = M[i][6];
            for (int j = i + 1; j < 6; j++) s -= M[i][j] * x0[j];
            x0[i] = s / M[i][i];
        }

        double nx0 = 0.0, nx = 0.0;
        float xf[6];
        for (int i = 0; i < 6; i++) {
            xf[i] = ws[16 + i];
            nx0 += x0[i] * x0[i];
            nx  += (double)xf[i] * (double)xf[i];
        }
        nx0 = sqrt(nx0); nx = sqrt(nx);
        bool convold = (ws[12] != 0.f);
        bool c2 = convold || (new_cost < 1e-3) || (nx0 < 1e-8 * (1e-8 + nx));
        float xn[6];
        for (int i = 0; i < 6; i++)
            xn[i] = c2 ? xf[i] : (float)((double)xf[i] - x0[i]);
        for (int i = 0; i < 6; i++) ws[16 + i] = xn[i];
        ws[12] = c2 ? 1.f : 0.f;
        if (!convold) ws[13] = (float)new_cost;

        float T[16];
        exp_se3_f32(xn, T);
        ws[0] = T[0]; ws[1] = T[1]; ws[2]  = T[2];
        ws[3] = T[4]; ws[4] = T[5]; ws[5]  = T[6];
        ws[6] = T[8]; ws[7] = T[9]; ws[8]  = T[10];
        ws[9] = T[3]; ws[10] = T[7]; ws[11] = T[11];

        if (final_iter) {
            for (int i = 0; i < 16; i++) out[i] = T[i];
            out[16] = ws[13];
        }
    }
}

extern "C" void kernel_launch(void* const* d_in, const int* in_sizes, int n_in,
                              void* d_out, int out_size, void* d_ws, size_t ws_size,
                              hipStream_t stream) {
    const float* depth_ref      = (const float*)d_in[0];
    const float* normals_ref    = (const float*)d_in[1];
    const float* gray_ref       = (const float*)d_in[2];
    const float* gray_target    = (const float*)d_in[3];
    const float* points_target  = (const float*)d_in[4];
    const float* normals_target = (const float*)d_in[5];
    const float* K              = (const float*)d_in[6];
    float* ws  = (float*)d_ws;
    float* out = (float*)d_out;

    bool big = ws_size >= (size_t)WS_BIG_END * sizeof(float);
    if (big) {
        hipLaunchKernelGGL((pack_init<1>), dim3(NB_B), dim3(TPB_B), 0, stream,
                           depth_ref, normals_ref, gray_target,
                           points_target, normals_target, ws);
        for (int it = 0; it < 20; ++it) {
            hipLaunchKernelGGL((map_reduce<1>), dim3(NB_B), dim3(TPB_B), 0, stream,
                               depth_ref, normals_ref, gray_ref, gray_target,
                               points_target, normals_target, K, ws);
            hipLaunchKernelGGL(solve_update, dim3(1), dim3(TPB_C), 0, stream,
                               ws, out, (it == 19) ? 1 : 0);
        }
    } else {
        hipLaunchKernelGGL((pack_init<0>), dim3(NB_B), dim3(TPB_B), 0, stream,
                           depth_ref, normals_ref, gray_target,
                           points_target, normals_target, ws);
        for (int it = 0; it < 20; ++it) {
            hipLaunchKernelGGL((map_reduce<0>), dim3(NB_B), dim3(TPB_B), 0, stream,
                               depth_ref, normals_ref, gray_ref, gray_target,
                               points_target, normals_target, K, ws);
            hipLaunchKernelGGL(solve_update, dim3(1), dim3(TPB_C), 0, stream,
                               ws, out, (it == 19) ? 1 : 0);
        }
    }
}